// Round 2
// baseline (535.426 us; speedup 1.0000x reference)
//
#include <hip/hip_runtime.h>
#include <math.h>

#define TWO_PI 6.28318530717958647692f

__device__ __forceinline__ void cmac(float2& a, const float2 b, const float2 c) {
  a.x = fmaf(b.x, c.x, fmaf(-b.y, c.y, a.x));
  a.y = fmaf(b.x, c.y, fmaf(b.y, c.x, a.y));
}
__device__ __forceinline__ float2 cmul(const float2 a, const float2 b) {
  return make_float2(fmaf(a.x, b.x, -a.y * b.y), fmaf(a.x, b.y, a.y * b.x));
}

// ---------------------------------------------------------------------------
// F1: pruned DFT along H.  x:(B,C,256,256,4) -> G[(b*32+c)*2+dual][k(64)][y(256)]
// grid 4096 = 128 images * 32 w-tiles(8), block 256.
// Twiddles via per-thread register recurrence (anchored every 16 steps).
// ---------------------------------------------------------------------------
__global__ __launch_bounds__(256) void f1_dft_h(const float* __restrict__ x,
                                                float* __restrict__ G) {
  __shared__ float2 yf[64][4][2][8];  // [n1][r][dual][w]
  const int t = threadIdx.x;
  const int bid = blockIdx.x;
  const int img = bid >> 5;            // b*32+c
  const int w0  = (bid & 31) << 3;     // 8-column tile
  const float4* __restrict__ xb = (const float4*)x + (size_t)img * 65536 + w0;
  {
    const int wl  = t & 7;
    const int n1g = t >> 3;            // [0,32)
#pragma unroll
    for (int ii = 0; ii < 2; ++ii) {
      const int n1 = n1g * 2 + ii;
      const float4 v0 = xb[(size_t)(n1)*256 + wl];
      const float4 v1 = xb[(size_t)(n1 + 64) * 256 + wl];
      const float4 v2 = xb[(size_t)(n1 + 128) * 256 + wl];
      const float4 v3 = xb[(size_t)(n1 + 192) * 256 + wl];
      {  // dual 0: (comp0, comp3)
        const float sx = v0.x + v2.x, sy = v0.w + v2.w;
        const float dx = v0.x - v2.x, dy = v0.w - v2.w;
        const float ux = v1.x + v3.x, uy = v1.w + v3.w;
        const float ex = v1.x - v3.x, ey = v1.w - v3.w;
        yf[n1][0][0][wl] = make_float2(sx + ux, sy + uy);
        yf[n1][2][0][wl] = make_float2(sx - ux, sy - uy);
        yf[n1][1][0][wl] = make_float2(dx + ey, dy - ex);
        yf[n1][3][0][wl] = make_float2(dx - ey, dy + ex);
      }
      {  // dual 1: (comp1, comp2)
        const float sx = v0.y + v2.y, sy = v0.z + v2.z;
        const float dx = v0.y - v2.y, dy = v0.z - v2.z;
        const float ux = v1.y + v3.y, uy = v1.z + v3.z;
        const float ex = v1.y - v3.y, ey = v1.z - v3.z;
        yf[n1][0][1][wl] = make_float2(sx + ux, sy + uy);
        yf[n1][2][1][wl] = make_float2(sx - ux, sy - uy);
        yf[n1][1][1][wl] = make_float2(dx + ey, dy - ex);
        yf[n1][3][1][wl] = make_float2(dx - ey, dy + ex);
      }
    }
  }
  __syncthreads();
  const int wl    = t & 7;
  const int dual  = (t >> 3) & 1;
  const int kslot = t >> 4;            // [0,16)
  const int r     = kslot & 3;
  float2 st[4], st16[4], anc[4], acc[4];
#pragma unroll
  for (int m = 0; m < 4; ++m) {
    const int ki = kslot + (m << 4);
    const float fr = (float)((ki < 32) ? ki : ki - 64);
    float sv, cv;
    sincosf(-TWO_PI * fr * (1.0f / 256.0f), &sv, &cv);
    st[m] = make_float2(cv, sv);
    sincosf(-TWO_PI * fr * (1.0f / 16.0f), &sv, &cv);
    st16[m] = make_float2(cv, sv);
    anc[m] = make_float2(1.f, 0.f);
    acc[m] = make_float2(0.f, 0.f);
  }
#pragma unroll 1
  for (int c4 = 0; c4 < 4; ++c4) {
    float2 w[4];
#pragma unroll
    for (int m = 0; m < 4; ++m) w[m] = anc[m];
#pragma unroll
    for (int tt = 0; tt < 16; ++tt) {
      const float2 yv = yf[c4 * 16 + tt][r][dual][wl];
#pragma unroll
      for (int m = 0; m < 4; ++m) {
        cmac(acc[m], yv, w[m]);
        w[m] = cmul(w[m], st[m]);
      }
    }
#pragma unroll
    for (int m = 0; m < 4; ++m) anc[m] = cmul(anc[m], st16[m]);
  }
  float2* __restrict__ Gp = (float2*)G;
  const size_t base = ((size_t)(img * 2 + dual) * 64) * 256 + w0 + wl;
#pragma unroll
  for (int m = 0; m < 4; ++m)
    Gp[base + (size_t)(kslot + (m << 4)) * 256] = acc[m];
}

// ---------------------------------------------------------------------------
// F2: pruned DFT along W on kept rows. G -> modes_in[b][s][c][x'][y']
// grid 1024 (16 rows/block), block 256; 4 modes/thread, register twiddles.
// ---------------------------------------------------------------------------
__global__ __launch_bounds__(256) void f2_dft_w(const float* __restrict__ G,
                                                float* __restrict__ mi) {
  __shared__ float2 yf[16][65][4];  // [trow][n1][r], 65-pad -> conflict-free
  const int t = threadIdx.x;
  const int row0 = blockIdx.x * 16;
  for (int idx = t; idx < 1024; idx += 256) {
    const int tr = idx >> 6, n1 = idx & 63;
    const float2* __restrict__ Gp = (const float2*)G + (size_t)(row0 + tr) * 256;
    const float2 z0 = Gp[n1], z1 = Gp[n1 + 64], z2 = Gp[n1 + 128], z3 = Gp[n1 + 192];
    const float sx = z0.x + z2.x, sy = z0.y + z2.y;
    const float dx = z0.x - z2.x, dy = z0.y - z2.y;
    const float ux = z1.x + z3.x, uy = z1.y + z3.y;
    const float ex = z1.x - z3.x, ey = z1.y - z3.y;
    yf[tr][n1][0] = make_float2(sx + ux, sy + uy);
    yf[tr][n1][2] = make_float2(sx - ux, sy - uy);
    yf[tr][n1][1] = make_float2(dx + ey, dy - ex);
    yf[tr][n1][3] = make_float2(dx - ey, dy + ex);
  }
  __syncthreads();
  const int trow  = t >> 4;   // [0,16)
  const int kslot = t & 15;
  const int r     = kslot & 3;
  float2 st[4], st16[4], anc[4], acc[4];
#pragma unroll
  for (int m = 0; m < 4; ++m) {
    const int ki = kslot + (m << 4);
    const float fr = (float)((ki < 32) ? ki : ki - 64);
    float sv, cv;
    sincosf(-TWO_PI * fr * (1.0f / 256.0f), &sv, &cv);
    st[m] = make_float2(cv, sv);
    sincosf(-TWO_PI * fr * (1.0f / 16.0f), &sv, &cv);
    st16[m] = make_float2(cv, sv);
    anc[m] = make_float2(1.f, 0.f);
    acc[m] = make_float2(0.f, 0.f);
  }
#pragma unroll 1
  for (int c4 = 0; c4 < 4; ++c4) {
    float2 w[4];
#pragma unroll
    for (int m = 0; m < 4; ++m) w[m] = anc[m];
#pragma unroll
    for (int tt = 0; tt < 16; ++tt) {
      const float2 yv = yf[trow][c4 * 16 + tt][r];
#pragma unroll
      for (int m = 0; m < 4; ++m) {
        cmac(acc[m], yv, w[m]);
        w[m] = cmul(w[m], st[m]);
      }
    }
#pragma unroll
    for (int m = 0; m < 4; ++m) anc[m] = cmul(anc[m], st16[m]);
  }
  const int row  = row0 + trow;       // ((img*2+dual)*64 + kx)
  const int kx   = row & 63;
  const int dual = (row >> 6) & 1;
  const int bc   = row >> 7;
  const int b = bc >> 5, cc = bc & 31;
  const int sRe = dual ? 1 : 0;
  const int sIm = dual ? 2 : 3;
#pragma unroll
  for (int m = 0; m < 4; ++m) {
    const int kyi = kslot + (m << 4);
    const size_t moff = (size_t)kx * 64 + kyi;
    mi[(((size_t)(b * 4 + sRe)) * 32 + cc) * 4096 + moff] = acc[m].x;
    mi[(((size_t)(b * 4 + sIm)) * 32 + cc) * 4096 + moff] = acc[m].y;
  }
}

// ---------------------------------------------------------------------------
// EIN: per-mode Clifford mix. 32-mode tiles, 512 threads (32q x 16o).
// Weights streamed exactly once, 128B-coalesced.
// grid 256 = 128 mode-tiles * 2 o-halves.
// ---------------------------------------------------------------------------
__global__ __launch_bounds__(512) void ein_k(const float* __restrict__ mi,
                                             const float* __restrict__ wgt,
                                             float* __restrict__ mo) {
  __shared__ float si[4][128][32];  // [b][i=s*32+c][q]  64KB
  const int t = threadIdx.x;
  const int bid = blockIdx.x;
  const int m0 = (bid >> 1) << 5;
  const int oh = bid & 1;
  for (int idx = t; idx < 16384; idx += 512) {
    const int q = idx & 31, i = (idx >> 5) & 127, b = idx >> 12;
    si[b][i][q] = mi[((size_t)b * 128 + i) * 4096 + m0 + q];
  }
  __syncthreads();
  const int q = t & 31;
  const int o = oh * 16 + (t >> 5);
  float acc[4][4];
#pragma unroll
  for (int b = 0; b < 4; ++b)
#pragma unroll
    for (int r = 0; r < 4; ++r) acc[b][r] = 0.f;
#pragma unroll 2
  for (int c = 0; c < 32; ++c) {
    float wv[4];
#pragma unroll
    for (int j = 0; j < 4; ++j)
      wv[j] = wgt[(((size_t)j * 32 + o) * 32 + c) * 4096 + m0 + q];
#pragma unroll
    for (int b = 0; b < 4; ++b) {
      const float iv0 = si[b][c][q];
      const float iv1 = si[b][32 + c][q];
      const float iv2 = si[b][64 + c][q];
      const float iv3 = si[b][96 + c][q];
      acc[b][0] += wv[0] * iv0 + wv[1] * iv1 + wv[2] * iv2 - wv[3] * iv3;
      acc[b][1] += wv[1] * iv0 + wv[0] * iv1 - wv[3] * iv2 + wv[2] * iv3;
      acc[b][2] += wv[2] * iv0 + wv[3] * iv1 + wv[0] * iv2 - wv[1] * iv3;
      acc[b][3] += wv[3] * iv0 + wv[2] * iv1 - wv[1] * iv2 + wv[0] * iv3;
    }
  }
#pragma unroll
  for (int b = 0; b < 4; ++b)
#pragma unroll
    for (int r = 0; r < 4; ++r)
      mo[(((size_t)b * 4 + r) * 32 + o) * 4096 + m0 + q] = acc[b][r];
}

// ---------------------------------------------------------------------------
// I1: inverse DFT along W (64->256). Register twiddles + (-i)^n1 half-fold.
// grid 4096 (4 rows/block), block 256
// ---------------------------------------------------------------------------
__global__ __launch_bounds__(256) void i1_idft_w(const float* __restrict__ mo,
                                                 float* __restrict__ T) {
  __shared__ float2 srow[4][64];
  const int t = threadIdx.x;
  const int trow = t >> 6, lane = t & 63;
  const int row = blockIdx.x * 4 + trow;  // ((bo*2+dual)*64 + kx)
  const int kx = row & 63;
  const int dual = (row >> 6) & 1;
  const int bo = row >> 7;
  const int b = bo >> 5, o = bo & 31;
  const int rA = dual ? 1 : 0;
  const int rB = dual ? 2 : 3;
  const size_t ibase = (size_t)kx * 64 + lane;
  srow[trow][lane] = make_float2(mo[(((size_t)b * 4 + rA) * 32 + o) * 4096 + ibase],
                                 mo[(((size_t)b * 4 + rB) * 32 + o) * 4096 + ibase]);
  __syncthreads();
  const int n1 = lane;
  float sv, cv;
  sincosf(TWO_PI * (float)n1 * (1.0f / 256.0f), &sv, &cv);
  const float2 w1 = make_float2(cv, sv);
  sincosf(TWO_PI * (float)n1 * (1.0f / 64.0f), &sv, &cv);
  const float2 step = make_float2(cv, sv);
  float2 w[4];
  w[0] = make_float2(1.f, 0.f);
  w[1] = w1;
  w[2] = cmul(w1, w1);
  w[3] = cmul(w[2], w1);
  float2 accA[4], accB[4];
#pragma unroll
  for (int r = 0; r < 4; ++r) {
    accA[r] = make_float2(0.f, 0.f);
    accB[r] = make_float2(0.f, 0.f);
  }
#pragma unroll
  for (int tt = 0; tt < 8; ++tt)
#pragma unroll
    for (int r = 0; r < 4; ++r) {
      cmac(accA[r], srow[trow][r + 4 * tt], w[r]);
      w[r] = cmul(w[r], step);
    }
#pragma unroll
  for (int tt = 8; tt < 16; ++tt)
#pragma unroll
    for (int r = 0; r < 4; ++r) {
      cmac(accB[r], srow[trow][r + 4 * tt], w[r]);
      w[r] = cmul(w[r], step);
    }
  const int qq = n1 & 3;
  const float2 rot = make_float2((float)((qq == 0) - (qq == 2)),
                                 (float)((qq == 3) - (qq == 1)));  // (-i)^n1
  float2 V[4];
#pragma unroll
  for (int r = 0; r < 4; ++r) {
    const float2 Br = cmul(accB[r], rot);
    V[r] = make_float2(accA[r].x + Br.x, accA[r].y + Br.y);
  }
  const float sx = V[0].x + V[2].x, sy = V[0].y + V[2].y;
  const float dx = V[0].x - V[2].x, dy = V[0].y - V[2].y;
  const float ux = V[1].x + V[3].x, uy = V[1].y + V[3].y;
  const float ex = V[1].x - V[3].x, ey = V[1].y - V[3].y;
  float2* __restrict__ Tp = (float2*)T + (size_t)row * 256;
  Tp[n1]       = make_float2(sx + ux, sy + uy);
  Tp[n1 + 64]  = make_float2(dx - ey, dy + ex);
  Tp[n1 + 128] = make_float2(sx - ux, sy - uy);
  Tp[n1 + 192] = make_float2(dx + ey, dy - ex);
}

// ---------------------------------------------------------------------------
// I2: inverse DFT along H (64->256) + interleave + 1/65536 scale -> out
// grid 2048 = 128 images * 16 w-tiles(16), block 256; register twiddles.
// ---------------------------------------------------------------------------
__global__ __launch_bounds__(256) void i2_idft_h(const float* __restrict__ T,
                                                 float* __restrict__ out) {
  __shared__ float2 Tl[2][64][16];
  const int t = threadIdx.x;
  const int bid = blockIdx.x;
  const int bo = bid >> 4;
  const int w0 = (bid & 15) << 4;
  const float2* __restrict__ Tp = (const float2*)T + (size_t)bo * 2 * 16384;
  for (int idx = t; idx < 2048; idx += 256) {
    const int ww = idx & 15, kxi = (idx >> 4) & 63, dual = idx >> 10;
    Tl[dual][kxi][ww] = Tp[((size_t)dual * 64 + kxi) * 256 + w0 + ww];
  }
  __syncthreads();
  const int wl = t & 15;
  const int n1g = t >> 4;
  float4* __restrict__ op = (float4*)out + (size_t)bo * 65536 + w0 + wl;
  const float sc = 1.0f / 65536.0f;
#pragma unroll 1
  for (int ii = 0; ii < 4; ++ii) {
    const int n1 = n1g * 4 + ii;
    float sv, cv;
    sincosf(TWO_PI * (float)n1 * (1.0f / 256.0f), &sv, &cv);
    const float2 w1 = make_float2(cv, sv);
    sincosf(TWO_PI * (float)n1 * (1.0f / 64.0f), &sv, &cv);
    const float2 step = make_float2(cv, sv);
    float2 w[4];
    w[0] = make_float2(1.f, 0.f);
    w[1] = w1;
    w[2] = cmul(w1, w1);
    w[3] = cmul(w[2], w1);
    float2 accA[2][4], accB[2][4];
#pragma unroll
    for (int d = 0; d < 2; ++d)
#pragma unroll
      for (int r = 0; r < 4; ++r) {
        accA[d][r] = make_float2(0.f, 0.f);
        accB[d][r] = make_float2(0.f, 0.f);
      }
#pragma unroll
    for (int tt = 0; tt < 8; ++tt)
#pragma unroll
      for (int r = 0; r < 4; ++r) {
        const int kxi = r + 4 * tt;
        cmac(accA[0][r], Tl[0][kxi][wl], w[r]);
        cmac(accA[1][r], Tl[1][kxi][wl], w[r]);
        w[r] = cmul(w[r], step);
      }
#pragma unroll
    for (int tt = 8; tt < 16; ++tt)
#pragma unroll
      for (int r = 0; r < 4; ++r) {
        const int kxi = r + 4 * tt;
        cmac(accB[0][r], Tl[0][kxi][wl], w[r]);
        cmac(accB[1][r], Tl[1][kxi][wl], w[r]);
        w[r] = cmul(w[r], step);
      }
    const int qq = n1 & 3;
    const float2 rot = make_float2((float)((qq == 0) - (qq == 2)),
                                   (float)((qq == 3) - (qq == 1)));  // (-i)^n1
    float2 res[2][4];
#pragma unroll
    for (int dual = 0; dual < 2; ++dual) {
      float2 V[4];
#pragma unroll
      for (int r = 0; r < 4; ++r) {
        const float2 Br = cmul(accB[dual][r], rot);
        V[r] = make_float2(accA[dual][r].x + Br.x, accA[dual][r].y + Br.y);
      }
      const float sx = V[0].x + V[2].x, sy = V[0].y + V[2].y;
      const float dx = V[0].x - V[2].x, dy = V[0].y - V[2].y;
      const float ux = V[1].x + V[3].x, uy = V[1].y + V[3].y;
      const float ex = V[1].x - V[3].x, ey = V[1].y - V[3].y;
      res[dual][0] = make_float2(sx + ux, sy + uy);
      res[dual][1] = make_float2(dx - ey, dy + ex);
      res[dual][2] = make_float2(sx - ux, sy - uy);
      res[dual][3] = make_float2(dx + ey, dy - ex);
    }
#pragma unroll
    for (int n2 = 0; n2 < 4; ++n2) {
      const int h = n1 + (n2 << 6);
      const float2 o1 = res[0][n2], o2 = res[1][n2];
      op[(size_t)h * 256] = make_float4(o1.x * sc, o2.x * sc, o2.y * sc, o1.y * sc);
    }
  }
}

extern "C" void kernel_launch(void* const* d_in, const int* in_sizes, int n_in,
                              void* d_out, int out_size, void* d_ws, size_t ws_size,
                              hipStream_t stream) {
  const float* x = (const float*)d_in[0];
  const float* wgt = (const float*)d_in[1];
  float* out = (float*)d_out;
  float* G  = (float*)d_ws;        // 8,388,608 floats (33.5 MB), reused as T
  float* mi = G + 8388608;         // 2,097,152 floats
  float* mo = mi + 2097152;        // 2,097,152 floats

  hipLaunchKernelGGL(f1_dft_h, dim3(4096), dim3(256), 0, stream, x, G);
  hipLaunchKernelGGL(f2_dft_w, dim3(1024), dim3(256), 0, stream, G, mi);
  hipLaunchKernelGGL(ein_k,    dim3(256),  dim3(512), 0, stream, mi, wgt, mo);
  hipLaunchKernelGGL(i1_idft_w, dim3(4096), dim3(256), 0, stream, mo, G);
  hipLaunchKernelGGL(i2_idft_h, dim3(2048), dim3(256), 0, stream, G, out);
}

// Round 3
// 213.710 us; speedup vs baseline: 2.5054x; 2.5054x over previous
//
#include <hip/hip_runtime.h>
#include <math.h>

#define TWO_PI 6.28318530717958647692f

__device__ __forceinline__ void cmac(float2& a, const float2 b, const float2 c) {
  a.x = fmaf(b.x, c.x, fmaf(-b.y, c.y, a.x));
  a.y = fmaf(b.x, c.y, fmaf(b.y, c.x, a.y));
}
__device__ __forceinline__ float2 cmul(const float2 a, const float2 b) {
  return make_float2(fmaf(a.x, b.x, -a.y * b.y), fmaf(a.x, b.y, a.y * b.x));
}

// ---------------------------------------------------------------------------
// F1: pruned DFT along H.  x:(B,C,256,256,4) -> G[(b*32+c)*2+dual][k(64)][y(256)]
// grid 4096 = 128 images * 32 w-tiles(8), block 256.
// ---------------------------------------------------------------------------
__global__ __launch_bounds__(256) void f1_dft_h(const float* __restrict__ x,
                                                float* __restrict__ G) {
  __shared__ float2 yf[64][4][2][8];  // [n1][r][dual][w]
  const int t = threadIdx.x;
  const int bid = blockIdx.x;
  const int img = bid >> 5;            // b*32+c
  const int w0  = (bid & 31) << 3;     // 8-column tile
  const float4* __restrict__ xb = (const float4*)x + (size_t)img * 65536 + w0;
  {
    const int wl  = t & 7;
    const int n1g = t >> 3;            // [0,32)
#pragma unroll
    for (int ii = 0; ii < 2; ++ii) {
      const int n1 = n1g * 2 + ii;
      const float4 v0 = xb[(size_t)(n1)*256 + wl];
      const float4 v1 = xb[(size_t)(n1 + 64) * 256 + wl];
      const float4 v2 = xb[(size_t)(n1 + 128) * 256 + wl];
      const float4 v3 = xb[(size_t)(n1 + 192) * 256 + wl];
      {  // dual 0: (comp0, comp3)
        const float sx = v0.x + v2.x, sy = v0.w + v2.w;
        const float dx = v0.x - v2.x, dy = v0.w - v2.w;
        const float ux = v1.x + v3.x, uy = v1.w + v3.w;
        const float ex = v1.x - v3.x, ey = v1.w - v3.w;
        yf[n1][0][0][wl] = make_float2(sx + ux, sy + uy);
        yf[n1][2][0][wl] = make_float2(sx - ux, sy - uy);
        yf[n1][1][0][wl] = make_float2(dx + ey, dy - ex);
        yf[n1][3][0][wl] = make_float2(dx - ey, dy + ex);
      }
      {  // dual 1: (comp1, comp2)
        const float sx = v0.y + v2.y, sy = v0.z + v2.z;
        const float dx = v0.y - v2.y, dy = v0.z - v2.z;
        const float ux = v1.y + v3.y, uy = v1.z + v3.z;
        const float ex = v1.y - v3.y, ey = v1.z - v3.z;
        yf[n1][0][1][wl] = make_float2(sx + ux, sy + uy);
        yf[n1][2][1][wl] = make_float2(sx - ux, sy - uy);
        yf[n1][1][1][wl] = make_float2(dx + ey, dy - ex);
        yf[n1][3][1][wl] = make_float2(dx - ey, dy + ex);
      }
    }
  }
  __syncthreads();
  const int wl    = t & 7;
  const int dual  = (t >> 3) & 1;
  const int kslot = t >> 4;            // [0,16)
  const int r     = kslot & 3;
  float2 st[4], st16[4], anc[4], acc[4];
#pragma unroll
  for (int m = 0; m < 4; ++m) {
    const int ki = kslot + (m << 4);
    const float fr = (float)((ki < 32) ? ki : ki - 64);
    float sv, cv;
    sincosf(-TWO_PI * fr * (1.0f / 256.0f), &sv, &cv);
    st[m] = make_float2(cv, sv);
    sincosf(-TWO_PI * fr * (1.0f / 16.0f), &sv, &cv);
    st16[m] = make_float2(cv, sv);
    anc[m] = make_float2(1.f, 0.f);
    acc[m] = make_float2(0.f, 0.f);
  }
#pragma unroll 1
  for (int c4 = 0; c4 < 4; ++c4) {
    float2 w[4];
#pragma unroll
    for (int m = 0; m < 4; ++m) w[m] = anc[m];
#pragma unroll
    for (int tt = 0; tt < 16; ++tt) {
      const float2 yv = yf[c4 * 16 + tt][r][dual][wl];
#pragma unroll
      for (int m = 0; m < 4; ++m) {
        cmac(acc[m], yv, w[m]);
        w[m] = cmul(w[m], st[m]);
      }
    }
#pragma unroll
    for (int m = 0; m < 4; ++m) anc[m] = cmul(anc[m], st16[m]);
  }
  float2* __restrict__ Gp = (float2*)G;
  const size_t base = ((size_t)(img * 2 + dual) * 64) * 256 + w0 + wl;
#pragma unroll
  for (int m = 0; m < 4; ++m)
    Gp[base + (size_t)(kslot + (m << 4)) * 256] = acc[m];
}

// ---------------------------------------------------------------------------
// F2: pruned DFT along W on kept rows. G -> modes_in[b][s][c][x'][y']
// grid 1024 (16 rows/block), block 256; 4 modes/thread.
// ---------------------------------------------------------------------------
__global__ __launch_bounds__(256) void f2_dft_w(const float* __restrict__ G,
                                                float* __restrict__ mi) {
  __shared__ float2 yf[16][65][4];  // [trow][n1][r], 65-pad -> conflict-free
  const int t = threadIdx.x;
  const int row0 = blockIdx.x * 16;
  for (int idx = t; idx < 1024; idx += 256) {
    const int tr = idx >> 6, n1 = idx & 63;
    const float2* __restrict__ Gp = (const float2*)G + (size_t)(row0 + tr) * 256;
    const float2 z0 = Gp[n1], z1 = Gp[n1 + 64], z2 = Gp[n1 + 128], z3 = Gp[n1 + 192];
    const float sx = z0.x + z2.x, sy = z0.y + z2.y;
    const float dx = z0.x - z2.x, dy = z0.y - z2.y;
    const float ux = z1.x + z3.x, uy = z1.y + z3.y;
    const float ex = z1.x - z3.x, ey = z1.y - z3.y;
    yf[tr][n1][0] = make_float2(sx + ux, sy + uy);
    yf[tr][n1][2] = make_float2(sx - ux, sy - uy);
    yf[tr][n1][1] = make_float2(dx + ey, dy - ex);
    yf[tr][n1][3] = make_float2(dx - ey, dy + ex);
  }
  __syncthreads();
  const int trow  = t >> 4;   // [0,16)
  const int kslot = t & 15;
  const int r     = kslot & 3;
  float2 st[4], st16[4], anc[4], acc[4];
#pragma unroll
  for (int m = 0; m < 4; ++m) {
    const int ki = kslot + (m << 4);
    const float fr = (float)((ki < 32) ? ki : ki - 64);
    float sv, cv;
    sincosf(-TWO_PI * fr * (1.0f / 256.0f), &sv, &cv);
    st[m] = make_float2(cv, sv);
    sincosf(-TWO_PI * fr * (1.0f / 16.0f), &sv, &cv);
    st16[m] = make_float2(cv, sv);
    anc[m] = make_float2(1.f, 0.f);
    acc[m] = make_float2(0.f, 0.f);
  }
#pragma unroll 1
  for (int c4 = 0; c4 < 4; ++c4) {
    float2 w[4];
#pragma unroll
    for (int m = 0; m < 4; ++m) w[m] = anc[m];
#pragma unroll
    for (int tt = 0; tt < 16; ++tt) {
      const float2 yv = yf[trow][c4 * 16 + tt][r];
#pragma unroll
      for (int m = 0; m < 4; ++m) {
        cmac(acc[m], yv, w[m]);
        w[m] = cmul(w[m], st[m]);
      }
    }
#pragma unroll
    for (int m = 0; m < 4; ++m) anc[m] = cmul(anc[m], st16[m]);
  }
  const int row  = row0 + trow;       // ((img*2+dual)*64 + kx)
  const int kx   = row & 63;
  const int dual = (row >> 6) & 1;
  const int bc   = row >> 7;
  const int b = bc >> 5, cc = bc & 31;
  const int sRe = dual ? 1 : 0;
  const int sIm = dual ? 2 : 3;
#pragma unroll
  for (int m = 0; m < 4; ++m) {
    const int kyi = kslot + (m << 4);
    const size_t moff = (size_t)kx * 64 + kyi;
    mi[(((size_t)(b * 4 + sRe)) * 32 + cc) * 4096 + moff] = acc[m].x;
    mi[(((size_t)(b * 4 + sIm)) * 32 + cc) * 4096 + moff] = acc[m].y;
  }
}

// ---------------------------------------------------------------------------
// EIN: per-mode Clifford mix. 32-mode tiles, 512 threads (32q x 16o).
// grid 256 = 128 mode-tiles * 2 o-halves.
// ---------------------------------------------------------------------------
__global__ __launch_bounds__(512) void ein_k(const float* __restrict__ mi,
                                             const float* __restrict__ wgt,
                                             float* __restrict__ mo) {
  __shared__ float si[4][128][32];  // [b][i=s*32+c][q]  64KB
  const int t = threadIdx.x;
  const int bid = blockIdx.x;
  const int m0 = (bid >> 1) << 5;
  const int oh = bid & 1;
  for (int idx = t; idx < 16384; idx += 512) {
    const int q = idx & 31, i = (idx >> 5) & 127, b = idx >> 12;
    si[b][i][q] = mi[((size_t)b * 128 + i) * 4096 + m0 + q];
  }
  __syncthreads();
  const int q = t & 31;
  const int o = oh * 16 + (t >> 5);
  float acc[4][4];
#pragma unroll
  for (int b = 0; b < 4; ++b)
#pragma unroll
    for (int r = 0; r < 4; ++r) acc[b][r] = 0.f;
#pragma unroll 2
  for (int c = 0; c < 32; ++c) {
    float wv[4];
#pragma unroll
    for (int j = 0; j < 4; ++j)
      wv[j] = wgt[(((size_t)j * 32 + o) * 32 + c) * 4096 + m0 + q];
#pragma unroll
    for (int b = 0; b < 4; ++b) {
      const float iv0 = si[b][c][q];
      const float iv1 = si[b][32 + c][q];
      const float iv2 = si[b][64 + c][q];
      const float iv3 = si[b][96 + c][q];
      acc[b][0] += wv[0] * iv0 + wv[1] * iv1 + wv[2] * iv2 - wv[3] * iv3;
      acc[b][1] += wv[1] * iv0 + wv[0] * iv1 - wv[3] * iv2 + wv[2] * iv3;
      acc[b][2] += wv[2] * iv0 + wv[3] * iv1 + wv[0] * iv2 - wv[1] * iv3;
      acc[b][3] += wv[3] * iv0 + wv[2] * iv1 - wv[1] * iv2 + wv[0] * iv3;
    }
  }
#pragma unroll
  for (int b = 0; b < 4; ++b)
#pragma unroll
    for (int r = 0; r < 4; ++r)
      mo[(((size_t)b * 4 + r) * 32 + o) * 4096 + m0 + q] = acc[b][r];
}

// ---------------------------------------------------------------------------
// I1: inverse DFT along W (64->256). Register twiddles + (-i)^n1 half-fold.
// grid 4096 (4 rows/block), block 256
// ---------------------------------------------------------------------------
__global__ __launch_bounds__(256) void i1_idft_w(const float* __restrict__ mo,
                                                 float* __restrict__ T) {
  __shared__ float2 srow[4][64];
  const int t = threadIdx.x;
  const int trow = t >> 6, lane = t & 63;
  const int row = blockIdx.x * 4 + trow;  // ((bo*2+dual)*64 + kx)
  const int kx = row & 63;
  const int dual = (row >> 6) & 1;
  const int bo = row >> 7;
  const int b = bo >> 5, o = bo & 31;
  const int rA = dual ? 1 : 0;
  const int rB = dual ? 2 : 3;
  const size_t ibase = (size_t)kx * 64 + lane;
  srow[trow][lane] = make_float2(mo[(((size_t)b * 4 + rA) * 32 + o) * 4096 + ibase],
                                 mo[(((size_t)b * 4 + rB) * 32 + o) * 4096 + ibase]);
  __syncthreads();
  const int n1 = lane;
  float sv, cv;
  sincosf(TWO_PI * (float)n1 * (1.0f / 256.0f), &sv, &cv);
  const float2 w1 = make_float2(cv, sv);
  sincosf(TWO_PI * (float)n1 * (1.0f / 64.0f), &sv, &cv);
  const float2 step = make_float2(cv, sv);
  float2 w[4];
  w[0] = make_float2(1.f, 0.f);
  w[1] = w1;
  w[2] = cmul(w1, w1);
  w[3] = cmul(w[2], w1);
  float2 accA[4], accB[4];
#pragma unroll
  for (int r = 0; r < 4; ++r) {
    accA[r] = make_float2(0.f, 0.f);
    accB[r] = make_float2(0.f, 0.f);
  }
#pragma unroll
  for (int tt = 0; tt < 8; ++tt)
#pragma unroll
    for (int r = 0; r < 4; ++r) {
      cmac(accA[r], srow[trow][r + 4 * tt], w[r]);
      w[r] = cmul(w[r], step);
    }
#pragma unroll
  for (int tt = 8; tt < 16; ++tt)
#pragma unroll
    for (int r = 0; r < 4; ++r) {
      cmac(accB[r], srow[trow][r + 4 * tt], w[r]);
      w[r] = cmul(w[r], step);
    }
  const int qq = n1 & 3;
  const float2 rot = make_float2((float)((qq == 0) - (qq == 2)),
                                 (float)((qq == 3) - (qq == 1)));  // (-i)^n1
  float2 V[4];
#pragma unroll
  for (int r = 0; r < 4; ++r) {
    const float2 Br = cmul(accB[r], rot);
    V[r] = make_float2(accA[r].x + Br.x, accA[r].y + Br.y);
  }
  const float sx = V[0].x + V[2].x, sy = V[0].y + V[2].y;
  const float dx = V[0].x - V[2].x, dy = V[0].y - V[2].y;
  const float ux = V[1].x + V[3].x, uy = V[1].y + V[3].y;
  const float ex = V[1].x - V[3].x, ey = V[1].y - V[3].y;
  float2* __restrict__ Tp = (float2*)T + (size_t)row * 256;
  Tp[n1]       = make_float2(sx + ux, sy + uy);
  Tp[n1 + 64]  = make_float2(dx - ey, dy + ex);
  Tp[n1 + 128] = make_float2(sx - ux, sy - uy);
  Tp[n1 + 192] = make_float2(dx + ey, dy - ex);
}

// ---------------------------------------------------------------------------
// I2 (v3): inverse DFT along H (64->256) + interleave + 1/65536 scale -> out.
// Table twiddles (no serial FMA chain), integer index recurrence, acc[2][4]
// rotating accumulators (dep distance 4), tw read shared by both duals.
// grid 2048 = 128 images * 16 w-tiles(16), block 256.
// ---------------------------------------------------------------------------
__global__ __launch_bounds__(256) void i2_idft_h(const float* __restrict__ T,
                                                 float* __restrict__ out) {
  __shared__ float2 twc[256];       // e^{+2pi i t/256}
  __shared__ float2 Tl[2][64][16];
  const int t = threadIdx.x;
  {
    float sv, cv;
    sincosf(TWO_PI * (float)t * (1.0f / 256.0f), &sv, &cv);
    twc[t] = make_float2(cv, sv);
  }
  const int bid = blockIdx.x;
  const int bo = bid >> 4;
  const int w0 = (bid & 15) << 4;
  const float2* __restrict__ Tp = (const float2*)T + (size_t)bo * 2 * 16384;
  for (int idx = t; idx < 2048; idx += 256) {
    const int ww = idx & 15, kxi = (idx >> 4) & 63, dual = idx >> 10;
    Tl[dual][kxi][ww] = Tp[((size_t)dual * 64 + kxi) * 256 + w0 + ww];
  }
  __syncthreads();
  const int wl = t & 15;
  const int n1g = t >> 4;
  float4* __restrict__ op = (float4*)out + (size_t)bo * 65536 + w0 + wl;
  const float sc = 1.0f / 65536.0f;
#pragma unroll 1
  for (int ii = 0; ii < 4; ++ii) {
    const int n1 = n1g * 4 + ii;
    float2 acc[2][4];
#pragma unroll
    for (int d = 0; d < 2; ++d)
#pragma unroll
      for (int r = 0; r < 4; ++r) acc[d][r] = make_float2(0.f, 0.f);
    int idx = 0;  // (kxf*n1) & 255
#pragma unroll 8
    for (int kxi = 0; kxi < 32; ++kxi) {
      const float2 tv = twc[idx];
      const int r = kxi & 3;
      cmac(acc[0][r], Tl[0][kxi][wl], tv);
      cmac(acc[1][r], Tl[1][kxi][wl], tv);
      idx = (idx + n1) & 255;
    }
    idx = (idx + 192 * n1) & 255;  // jump: kxf = kxi + 192 for kxi >= 32
#pragma unroll 8
    for (int kxi = 32; kxi < 64; ++kxi) {
      const float2 tv = twc[idx];
      const int r = kxi & 3;
      cmac(acc[0][r], Tl[0][kxi][wl], tv);
      cmac(acc[1][r], Tl[1][kxi][wl], tv);
      idx = (idx + n1) & 255;
    }
    // radix-4 recombine: X[n1 + 64*n2] = sum_r i^{r*n2} * acc[r]
    float2 res[2][4];
#pragma unroll
    for (int dual = 0; dual < 2; ++dual) {
      const float sx = acc[dual][0].x + acc[dual][2].x, sy = acc[dual][0].y + acc[dual][2].y;
      const float dx = acc[dual][0].x - acc[dual][2].x, dy = acc[dual][0].y - acc[dual][2].y;
      const float ux = acc[dual][1].x + acc[dual][3].x, uy = acc[dual][1].y + acc[dual][3].y;
      const float ex = acc[dual][1].x - acc[dual][3].x, ey = acc[dual][1].y - acc[dual][3].y;
      res[dual][0] = make_float2(sx + ux, sy + uy);
      res[dual][1] = make_float2(dx - ey, dy + ex);   // d + i*e
      res[dual][2] = make_float2(sx - ux, sy - uy);
      res[dual][3] = make_float2(dx + ey, dy - ex);   // d - i*e
    }
#pragma unroll
    for (int n2 = 0; n2 < 4; ++n2) {
      const int h = n1 + (n2 << 6);
      const float2 o1 = res[0][n2], o2 = res[1][n2];
      op[(size_t)h * 256] = make_float4(o1.x * sc, o2.x * sc, o2.y * sc, o1.y * sc);
    }
  }
}

extern "C" void kernel_launch(void* const* d_in, const int* in_sizes, int n_in,
                              void* d_out, int out_size, void* d_ws, size_t ws_size,
                              hipStream_t stream) {
  const float* x = (const float*)d_in[0];
  const float* wgt = (const float*)d_in[1];
  float* out = (float*)d_out;
  float* G  = (float*)d_ws;        // 8,388,608 floats (33.5 MB), reused as T
  float* mi = G + 8388608;         // 2,097,152 floats
  float* mo = mi + 2097152;        // 2,097,152 floats

  hipLaunchKernelGGL(f1_dft_h, dim3(4096), dim3(256), 0, stream, x, G);
  hipLaunchKernelGGL(f2_dft_w, dim3(1024), dim3(256), 0, stream, G, mi);
  hipLaunchKernelGGL(ein_k,    dim3(256),  dim3(512), 0, stream, mi, wgt, mo);
  hipLaunchKernelGGL(i1_idft_w, dim3(4096), dim3(256), 0, stream, mo, G);
  hipLaunchKernelGGL(i2_idft_h, dim3(2048), dim3(256), 0, stream, G, out);
}

// Round 4
// 142.956 us; speedup vs baseline: 3.7454x; 1.4949x over previous
//
#include <hip/hip_runtime.h>
#include <math.h>

#define TWO_PI 6.28318530717958647692f

__device__ __forceinline__ void cmac(float2& a, const float2 b, const float2 c) {
  a.x = fmaf(b.x, c.x, fmaf(-b.y, c.y, a.x));
  a.y = fmaf(b.x, c.y, fmaf(b.y, c.x, a.y));
}
__device__ __forceinline__ float2 cmul(const float2 a, const float2 b) {
  return make_float2(fmaf(a.x, b.x, -a.y * b.y), fmaf(a.x, b.y, a.y * b.x));
}

// cos/sin(2*pi*k/16), k=0..15 (positive exponent convention)
#define W16_C {1.f, 0.92387953f, 0.70710678f, 0.38268343f, 0.f, -0.38268343f, -0.70710678f, -0.92387953f, -1.f, -0.92387953f, -0.70710678f, -0.38268343f, 0.f, 0.38268343f, 0.70710678f, 0.92387953f}
#define W16_S {0.f, 0.38268343f, 0.70710678f, 0.92387953f, 1.f, 0.92387953f, 0.70710678f, 0.38268343f, 0.f, -0.38268343f, -0.70710678f, -0.92387953f, -1.f, -0.92387953f, -0.70710678f, -0.38268343f}

// 16-point inverse-DFT bins for one p1 residue: X[p1+4*p2], p2=0..3, from 16
// classes a[c] (c = kxi mod 16).  All indices compile-time (forceinline+unroll).
__device__ __forceinline__ void idft16_p1(const float2* a, const int p1,
                                          float2* X) {
  const float WC[16] = W16_C;
  const float WS[16] = W16_S;
  float2 tt[4];
#pragma unroll
  for (int r1 = 0; r1 < 4; ++r1) {
    const float2 q0 = a[r1], q1 = a[r1 + 4], q2 = a[r1 + 8], q3 = a[r1 + 12];
    const float2 s = make_float2(q0.x + q2.x, q0.y + q2.y);
    const float2 d = make_float2(q0.x - q2.x, q0.y - q2.y);
    const float2 u = make_float2(q1.x + q3.x, q1.y + q3.y);
    const float2 e = make_float2(q1.x - q3.x, q1.y - q3.y);
    float2 in;
    if (p1 == 0)      in = make_float2(s.x + u.x, s.y + u.y);
    else if (p1 == 1) in = make_float2(d.x - e.y, d.y + e.x);
    else if (p1 == 2) in = make_float2(s.x - u.x, s.y - u.y);
    else              in = make_float2(d.x + e.y, d.y - e.x);
    const float wc = WC[(r1 * p1) & 15], ws = WS[(r1 * p1) & 15];
    tt[r1] = make_float2(fmaf(in.x, wc, -in.y * ws), fmaf(in.y, wc, in.x * ws));
  }
  const float2 s = make_float2(tt[0].x + tt[2].x, tt[0].y + tt[2].y);
  const float2 d = make_float2(tt[0].x - tt[2].x, tt[0].y - tt[2].y);
  const float2 u = make_float2(tt[1].x + tt[3].x, tt[1].y + tt[3].y);
  const float2 e = make_float2(tt[1].x - tt[3].x, tt[1].y - tt[3].y);
  X[0] = make_float2(s.x + u.x, s.y + u.y);
  X[1] = make_float2(d.x - e.y, d.y + e.x);
  X[2] = make_float2(s.x - u.x, s.y - u.y);
  X[3] = make_float2(d.x + e.y, d.y - e.x);
}

// ---------------------------------------------------------------------------
// F1 (v4): pruned DFT along H with mod-16 class accumulation.
// x:(B,C,256,256,4) -> G[(b*32+c)*2+dual][k(64)][y(256)] complex.
// Thread: (wl 8, dual 2, kb 16). 64 cmacs into acc[n1&15]; outputs kb+16m
// via 4 constant-twiddle bins D[0],D[1],D[14],D[15]. grid 4096, block 256.
// ---------------------------------------------------------------------------
__global__ __launch_bounds__(256) void f1_dft_h(const float* __restrict__ x,
                                                float* __restrict__ G) {
  __shared__ float2 twn[256];         // e^{-2pi i t/256}
  __shared__ float2 yf[64][4][2][8];  // [n1][r][dual][w]
  const int t = threadIdx.x;
  {
    float sv, cv;
    sincosf(-TWO_PI * (float)t * (1.0f / 256.0f), &sv, &cv);
    twn[t] = make_float2(cv, sv);
  }
  const int bid = blockIdx.x;
  const int img = bid >> 5;            // b*32+c
  const int w0  = (bid & 31) << 3;     // 8-column tile
  const float4* __restrict__ xb = (const float4*)x + (size_t)img * 65536 + w0;
  {
    const int wl  = t & 7;
    const int n1g = t >> 3;            // [0,32)
#pragma unroll
    for (int ii = 0; ii < 2; ++ii) {
      const int n1 = n1g * 2 + ii;
      const float4 v0 = xb[(size_t)(n1)*256 + wl];
      const float4 v1 = xb[(size_t)(n1 + 64) * 256 + wl];
      const float4 v2 = xb[(size_t)(n1 + 128) * 256 + wl];
      const float4 v3 = xb[(size_t)(n1 + 192) * 256 + wl];
      {  // dual 0: (comp0, comp3)
        const float sx = v0.x + v2.x, sy = v0.w + v2.w;
        const float dx = v0.x - v2.x, dy = v0.w - v2.w;
        const float ux = v1.x + v3.x, uy = v1.w + v3.w;
        const float ex = v1.x - v3.x, ey = v1.w - v3.w;
        yf[n1][0][0][wl] = make_float2(sx + ux, sy + uy);
        yf[n1][2][0][wl] = make_float2(sx - ux, sy - uy);
        yf[n1][1][0][wl] = make_float2(dx + ey, dy - ex);
        yf[n1][3][0][wl] = make_float2(dx - ey, dy + ex);
      }
      {  // dual 1: (comp1, comp2)
        const float sx = v0.y + v2.y, sy = v0.z + v2.z;
        const float dx = v0.y - v2.y, dy = v0.z - v2.z;
        const float ux = v1.y + v3.y, uy = v1.z + v3.z;
        const float ex = v1.y - v3.y, ey = v1.z - v3.z;
        yf[n1][0][1][wl] = make_float2(sx + ux, sy + uy);
        yf[n1][2][1][wl] = make_float2(sx - ux, sy - uy);
        yf[n1][1][1][wl] = make_float2(dx + ey, dy - ex);
        yf[n1][3][1][wl] = make_float2(dx - ey, dy + ex);
      }
    }
  }
  __syncthreads();
  const int wl   = t & 7;
  const int dual = (t >> 3) & 1;
  const int kb   = t >> 4;             // [0,16)
  const int r    = kb & 3;
  float2 acc[16];
#pragma unroll
  for (int c = 0; c < 16; ++c) acc[c] = make_float2(0.f, 0.f);
  int idx = 0;                         // (n1*kb) & 255
#pragma unroll
  for (int n1 = 0; n1 < 64; ++n1) {
    const float2 tv = twn[idx];
    const float2 yv = yf[n1][r][dual][wl];
    cmac(acc[n1 & 15], yv, tv);
    idx = (idx + kb) & 255;
  }
  // Outputs: slot kb+16m.  m=0 -> sum; m=1 -> conj-twiddle bin; m=2 -> +2c
  // bin; m=3 -> +c bin  (negative-freq fold factor i^c absorbed).
  const float WC[16] = W16_C;
  const float WS[16] = W16_S;
  float2 D0 = make_float2(0.f, 0.f), D1 = D0, D2 = D0, D3 = D0;
#pragma unroll
  for (int c = 0; c < 16; ++c) {
    const float2 a = acc[c];
    const float cc = WC[c], ss = WS[c];
    const float cc2 = WC[(2 * c) & 15], ss2 = WS[(2 * c) & 15];
    D0.x += a.x;                         D0.y += a.y;
    D1.x = fmaf(a.x, cc,  fmaf( a.y, ss,  D1.x));   // * e^{-2pi i c/16}
    D1.y = fmaf(a.y, cc,  fmaf(-a.x, ss,  D1.y));
    D2.x = fmaf(a.x, cc2, fmaf(-a.y, ss2, D2.x));   // * e^{+2pi i 2c/16}
    D2.y = fmaf(a.y, cc2, fmaf( a.x, ss2, D2.y));
    D3.x = fmaf(a.x, cc,  fmaf(-a.y, ss,  D3.x));   // * e^{+2pi i c/16}
    D3.y = fmaf(a.y, cc,  fmaf( a.x, ss,  D3.y));
  }
  float2* __restrict__ Gp = (float2*)G;
  const size_t base = ((size_t)(img * 2 + dual) * 64) * 256 + w0 + wl;
  Gp[base + (size_t)(kb)*256]      = D0;
  Gp[base + (size_t)(kb + 16)*256] = D1;
  Gp[base + (size_t)(kb + 32)*256] = D2;
  Gp[base + (size_t)(kb + 48)*256] = D3;
}

// ---------------------------------------------------------------------------
// F2: pruned DFT along W on kept rows. G -> modes_in[b][s][c][x'][y']
// grid 1024 (16 rows/block), block 256; 4 modes/thread.  (unchanged)
// ---------------------------------------------------------------------------
__global__ __launch_bounds__(256) void f2_dft_w(const float* __restrict__ G,
                                                float* __restrict__ mi) {
  __shared__ float2 yf[16][65][4];
  const int t = threadIdx.x;
  const int row0 = blockIdx.x * 16;
  for (int idx = t; idx < 1024; idx += 256) {
    const int tr = idx >> 6, n1 = idx & 63;
    const float2* __restrict__ Gp = (const float2*)G + (size_t)(row0 + tr) * 256;
    const float2 z0 = Gp[n1], z1 = Gp[n1 + 64], z2 = Gp[n1 + 128], z3 = Gp[n1 + 192];
    const float sx = z0.x + z2.x, sy = z0.y + z2.y;
    const float dx = z0.x - z2.x, dy = z0.y - z2.y;
    const float ux = z1.x + z3.x, uy = z1.y + z3.y;
    const float ex = z1.x - z3.x, ey = z1.y - z3.y;
    yf[tr][n1][0] = make_float2(sx + ux, sy + uy);
    yf[tr][n1][2] = make_float2(sx - ux, sy - uy);
    yf[tr][n1][1] = make_float2(dx + ey, dy - ex);
    yf[tr][n1][3] = make_float2(dx - ey, dy + ex);
  }
  __syncthreads();
  const int trow  = t >> 4;
  const int kslot = t & 15;
  const int r     = kslot & 3;
  float2 st[4], st16[4], anc[4], acc[4];
#pragma unroll
  for (int m = 0; m < 4; ++m) {
    const int ki = kslot + (m << 4);
    const float fr = (float)((ki < 32) ? ki : ki - 64);
    float sv, cv;
    sincosf(-TWO_PI * fr * (1.0f / 256.0f), &sv, &cv);
    st[m] = make_float2(cv, sv);
    sincosf(-TWO_PI * fr * (1.0f / 16.0f), &sv, &cv);
    st16[m] = make_float2(cv, sv);
    anc[m] = make_float2(1.f, 0.f);
    acc[m] = make_float2(0.f, 0.f);
  }
#pragma unroll 1
  for (int c4 = 0; c4 < 4; ++c4) {
    float2 w[4];
#pragma unroll
    for (int m = 0; m < 4; ++m) w[m] = anc[m];
#pragma unroll
    for (int tt = 0; tt < 16; ++tt) {
      const float2 yv = yf[trow][c4 * 16 + tt][r];
#pragma unroll
      for (int m = 0; m < 4; ++m) {
        cmac(acc[m], yv, w[m]);
        w[m] = cmul(w[m], st[m]);
      }
    }
#pragma unroll
    for (int m = 0; m < 4; ++m) anc[m] = cmul(anc[m], st16[m]);
  }
  const int row  = row0 + trow;
  const int kx   = row & 63;
  const int dual = (row >> 6) & 1;
  const int bc   = row >> 7;
  const int b = bc >> 5, cc = bc & 31;
  const int sRe = dual ? 1 : 0;
  const int sIm = dual ? 2 : 3;
#pragma unroll
  for (int m = 0; m < 4; ++m) {
    const int kyi = kslot + (m << 4);
    const size_t moff = (size_t)kx * 64 + kyi;
    mi[(((size_t)(b * 4 + sRe)) * 32 + cc) * 4096 + moff] = acc[m].x;
    mi[(((size_t)(b * 4 + sIm)) * 32 + cc) * 4096 + moff] = acc[m].y;
  }
}

// ---------------------------------------------------------------------------
// EIN: per-mode Clifford mix. 32-mode tiles, 512 threads (32q x 16o).
// grid 256.  (unchanged)
// ---------------------------------------------------------------------------
__global__ __launch_bounds__(512) void ein_k(const float* __restrict__ mi,
                                             const float* __restrict__ wgt,
                                             float* __restrict__ mo) {
  __shared__ float si[4][128][32];
  const int t = threadIdx.x;
  const int bid = blockIdx.x;
  const int m0 = (bid >> 1) << 5;
  const int oh = bid & 1;
  for (int idx = t; idx < 16384; idx += 512) {
    const int q = idx & 31, i = (idx >> 5) & 127, b = idx >> 12;
    si[b][i][q] = mi[((size_t)b * 128 + i) * 4096 + m0 + q];
  }
  __syncthreads();
  const int q = t & 31;
  const int o = oh * 16 + (t >> 5);
  float acc[4][4];
#pragma unroll
  for (int b = 0; b < 4; ++b)
#pragma unroll
    for (int r = 0; r < 4; ++r) acc[b][r] = 0.f;
#pragma unroll 2
  for (int c = 0; c < 32; ++c) {
    float wv[4];
#pragma unroll
    for (int j = 0; j < 4; ++j)
      wv[j] = wgt[(((size_t)j * 32 + o) * 32 + c) * 4096 + m0 + q];
#pragma unroll
    for (int b = 0; b < 4; ++b) {
      const float iv0 = si[b][c][q];
      const float iv1 = si[b][32 + c][q];
      const float iv2 = si[b][64 + c][q];
      const float iv3 = si[b][96 + c][q];
      acc[b][0] += wv[0] * iv0 + wv[1] * iv1 + wv[2] * iv2 - wv[3] * iv3;
      acc[b][1] += wv[1] * iv0 + wv[0] * iv1 - wv[3] * iv2 + wv[2] * iv3;
      acc[b][2] += wv[2] * iv0 + wv[3] * iv1 + wv[0] * iv2 - wv[1] * iv3;
      acc[b][3] += wv[3] * iv0 + wv[2] * iv1 - wv[1] * iv2 + wv[0] * iv3;
    }
  }
#pragma unroll
  for (int b = 0; b < 4; ++b)
#pragma unroll
    for (int r = 0; r < 4; ++r)
      mo[(((size_t)b * 4 + r) * 32 + o) * 4096 + m0 + q] = acc[b][r];
}

// ---------------------------------------------------------------------------
// I1: inverse DFT along W (64->256). Register twiddles + (-i)^n1 half-fold.
// grid 4096 (4 rows/block), block 256.  (unchanged)
// ---------------------------------------------------------------------------
__global__ __launch_bounds__(256) void i1_idft_w(const float* __restrict__ mo,
                                                 float* __restrict__ T) {
  __shared__ float2 srow[4][64];
  const int t = threadIdx.x;
  const int trow = t >> 6, lane = t & 63;
  const int row = blockIdx.x * 4 + trow;
  const int kx = row & 63;
  const int dual = (row >> 6) & 1;
  const int bo = row >> 7;
  const int b = bo >> 5, o = bo & 31;
  const int rA = dual ? 1 : 0;
  const int rB = dual ? 2 : 3;
  const size_t ibase = (size_t)kx * 64 + lane;
  srow[trow][lane] = make_float2(mo[(((size_t)b * 4 + rA) * 32 + o) * 4096 + ibase],
                                 mo[(((size_t)b * 4 + rB) * 32 + o) * 4096 + ibase]);
  __syncthreads();
  const int n1 = lane;
  float sv, cv;
  sincosf(TWO_PI * (float)n1 * (1.0f / 256.0f), &sv, &cv);
  const float2 w1 = make_float2(cv, sv);
  sincosf(TWO_PI * (float)n1 * (1.0f / 64.0f), &sv, &cv);
  const float2 step = make_float2(cv, sv);
  float2 w[4];
  w[0] = make_float2(1.f, 0.f);
  w[1] = w1;
  w[2] = cmul(w1, w1);
  w[3] = cmul(w[2], w1);
  float2 accA[4], accB[4];
#pragma unroll
  for (int r = 0; r < 4; ++r) {
    accA[r] = make_float2(0.f, 0.f);
    accB[r] = make_float2(0.f, 0.f);
  }
#pragma unroll
  for (int tt = 0; tt < 8; ++tt)
#pragma unroll
    for (int r = 0; r < 4; ++r) {
      cmac(accA[r], srow[trow][r + 4 * tt], w[r]);
      w[r] = cmul(w[r], step);
    }
#pragma unroll
  for (int tt = 8; tt < 16; ++tt)
#pragma unroll
    for (int r = 0; r < 4; ++r) {
      cmac(accB[r], srow[trow][r + 4 * tt], w[r]);
      w[r] = cmul(w[r], step);
    }
  const int qq = n1 & 3;
  const float2 rot = make_float2((float)((qq == 0) - (qq == 2)),
                                 (float)((qq == 3) - (qq == 1)));
  float2 V[4];
#pragma unroll
  for (int r = 0; r < 4; ++r) {
    const float2 Br = cmul(accB[r], rot);
    V[r] = make_float2(accA[r].x + Br.x, accA[r].y + Br.y);
  }
  const float sx = V[0].x + V[2].x, sy = V[0].y + V[2].y;
  const float dx = V[0].x - V[2].x, dy = V[0].y - V[2].y;
  const float ux = V[1].x + V[3].x, uy = V[1].y + V[3].y;
  const float ex = V[1].x - V[3].x, ey = V[1].y - V[3].y;
  float2* __restrict__ Tp = (float2*)T + (size_t)row * 256;
  Tp[n1]       = make_float2(sx + ux, sy + uy);
  Tp[n1 + 64]  = make_float2(dx - ey, dy + ex);
  Tp[n1 + 128] = make_float2(sx - ux, sy - uy);
  Tp[n1 + 192] = make_float2(dx + ey, dy - ex);
}

// ---------------------------------------------------------------------------
// I2 (v4): inverse DFT along H with mod-16 class accumulation.
// Thread (wl 16, n1 16): 64 iters -> acc[2][16]; all 16 p-shifts recovered by
// constant-twiddle 16-pt DFT (idft16_p1).  4x fewer LDS reads & FMAs than v3.
// grid 2048 = 128 images * 16 w-tiles(16), block 256.
// ---------------------------------------------------------------------------
__global__ __launch_bounds__(256) void i2_idft_h(const float* __restrict__ T,
                                                 float* __restrict__ out) {
  __shared__ float2 twc[256];       // e^{+2pi i t/256}
  __shared__ float2 Tl[2][64][16];
  const int t = threadIdx.x;
  {
    float sv, cv;
    sincosf(TWO_PI * (float)t * (1.0f / 256.0f), &sv, &cv);
    twc[t] = make_float2(cv, sv);
  }
  const int bid = blockIdx.x;
  const int bo = bid >> 4;
  const int w0 = (bid & 15) << 4;
  const float2* __restrict__ Tp = (const float2*)T + (size_t)bo * 32768;
  for (int idx = t; idx < 2048; idx += 256) {
    const int ww = idx & 15, kxi = (idx >> 4) & 63, dual = idx >> 10;
    Tl[dual][kxi][ww] = Tp[((size_t)dual * 64 + kxi) * 256 + w0 + ww];
  }
  __syncthreads();
  const int wl = t & 15;
  const int n1 = t >> 4;             // [0,16)
  float2 a0[16], a1[16];
#pragma unroll
  for (int c = 0; c < 16; ++c) {
    a0[c] = make_float2(0.f, 0.f);
    a1[c] = make_float2(0.f, 0.f);
  }
  int idx = 0;                       // (kxf*n1) & 255
#pragma unroll
  for (int kxi = 0; kxi < 64; ++kxi) {
    if (kxi == 32) idx = (idx + 192 * n1) & 255;   // kxf jump at the fold
    const float2 tv = twc[idx];
    cmac(a0[kxi & 15], Tl[0][kxi][wl], tv);
    cmac(a1[kxi & 15], Tl[1][kxi][wl], tv);
    idx = (idx + n1) & 255;
  }
  const float sc = 1.0f / 65536.0f;
  float4* __restrict__ op = (float4*)out + (size_t)bo * 65536 + w0 + wl;
#pragma unroll
  for (int p1 = 0; p1 < 4; ++p1) {
    float2 X0[4], X1[4];
    idft16_p1(a0, p1, X0);
    idft16_p1(a1, p1, X1);
#pragma unroll
    for (int p2 = 0; p2 < 4; ++p2) {
      const int h = n1 + 16 * (p1 + 4 * p2);
      op[(size_t)h * 256] = make_float4(X0[p2].x * sc, X1[p2].x * sc,
                                        X1[p2].y * sc, X0[p2].y * sc);
    }
  }
}

extern "C" void kernel_launch(void* const* d_in, const int* in_sizes, int n_in,
                              void* d_out, int out_size, void* d_ws, size_t ws_size,
                              hipStream_t stream) {
  const float* x = (const float*)d_in[0];
  const float* wgt = (const float*)d_in[1];
  float* out = (float*)d_out;
  float* G  = (float*)d_ws;        // 8,388,608 floats (33.5 MB), reused as T
  float* mi = G + 8388608;         // 2,097,152 floats
  float* mo = mi + 2097152;        // 2,097,152 floats

  hipLaunchKernelGGL(f1_dft_h, dim3(4096), dim3(256), 0, stream, x, G);
  hipLaunchKernelGGL(f2_dft_w, dim3(1024), dim3(256), 0, stream, G, mi);
  hipLaunchKernelGGL(ein_k,    dim3(256),  dim3(512), 0, stream, mi, wgt, mo);
  hipLaunchKernelGGL(i1_idft_w, dim3(4096), dim3(256), 0, stream, mo, G);
  hipLaunchKernelGGL(i2_idft_h, dim3(2048), dim3(256), 0, stream, G, out);
}

// Round 5
// 136.377 us; speedup vs baseline: 3.9261x; 1.0482x over previous
//
#include <hip/hip_runtime.h>
#include <math.h>

#define TWO_PI 6.28318530717958647692f

__device__ __forceinline__ void cmac(float2& a, const float2 b, const float2 c) {
  a.x = fmaf(b.x, c.x, fmaf(-b.y, c.y, a.x));
  a.y = fmaf(b.x, c.y, fmaf(b.y, c.x, a.y));
}

// cos/sin(2*pi*k/16), k=0..15 (positive exponent convention)
#define W16_C {1.f, 0.92387953f, 0.70710678f, 0.38268343f, 0.f, -0.38268343f, -0.70710678f, -0.92387953f, -1.f, -0.92387953f, -0.70710678f, -0.38268343f, 0.f, 0.38268343f, 0.70710678f, 0.92387953f}
#define W16_S {0.f, 0.38268343f, 0.70710678f, 0.92387953f, 1.f, 0.92387953f, 0.70710678f, 0.38268343f, 0.f, -0.38268343f, -0.70710678f, -0.92387953f, -1.f, -0.92387953f, -0.70710678f, -0.38268343f}

// 16-point +exponent DFT bins X[p1+4*p2], p2=0..3, from 16 classes a[c].
__device__ __forceinline__ void idft16_p1(const float2* a, const int p1,
                                          float2* X) {
  const float WC[16] = W16_C;
  const float WS[16] = W16_S;
  float2 tt[4];
#pragma unroll
  for (int r1 = 0; r1 < 4; ++r1) {
    const float2 q0 = a[r1], q1 = a[r1 + 4], q2 = a[r1 + 8], q3 = a[r1 + 12];
    const float2 s = make_float2(q0.x + q2.x, q0.y + q2.y);
    const float2 d = make_float2(q0.x - q2.x, q0.y - q2.y);
    const float2 u = make_float2(q1.x + q3.x, q1.y + q3.y);
    const float2 e = make_float2(q1.x - q3.x, q1.y - q3.y);
    float2 in;
    if (p1 == 0)      in = make_float2(s.x + u.x, s.y + u.y);
    else if (p1 == 1) in = make_float2(d.x - e.y, d.y + e.x);
    else if (p1 == 2) in = make_float2(s.x - u.x, s.y - u.y);
    else              in = make_float2(d.x + e.y, d.y - e.x);
    const float wc = WC[(r1 * p1) & 15], ws = WS[(r1 * p1) & 15];
    tt[r1] = make_float2(fmaf(in.x, wc, -in.y * ws), fmaf(in.y, wc, in.x * ws));
  }
  const float2 s = make_float2(tt[0].x + tt[2].x, tt[0].y + tt[2].y);
  const float2 d = make_float2(tt[0].x - tt[2].x, tt[0].y - tt[2].y);
  const float2 u = make_float2(tt[1].x + tt[3].x, tt[1].y + tt[3].y);
  const float2 e = make_float2(tt[1].x - tt[3].x, tt[1].y - tt[3].y);
  X[0] = make_float2(s.x + u.x, s.y + u.y);
  X[1] = make_float2(d.x - e.y, d.y + e.x);
  X[2] = make_float2(s.x - u.x, s.y - u.y);
  X[3] = make_float2(d.x + e.y, d.y - e.x);
}

// ---------------------------------------------------------------------------
// F1 (v4): pruned DFT along H with mod-16 class accumulation. (unchanged)
// grid 4096, block 256.
// ---------------------------------------------------------------------------
__global__ __launch_bounds__(256) void f1_dft_h(const float* __restrict__ x,
                                                float* __restrict__ G) {
  __shared__ float2 twn[256];         // e^{-2pi i t/256}
  __shared__ float2 yf[64][4][2][8];  // [n1][r][dual][w]
  const int t = threadIdx.x;
  {
    float sv, cv;
    sincosf(-TWO_PI * (float)t * (1.0f / 256.0f), &sv, &cv);
    twn[t] = make_float2(cv, sv);
  }
  const int bid = blockIdx.x;
  const int img = bid >> 5;
  const int w0  = (bid & 31) << 3;
  const float4* __restrict__ xb = (const float4*)x + (size_t)img * 65536 + w0;
  {
    const int wl  = t & 7;
    const int n1g = t >> 3;
#pragma unroll
    for (int ii = 0; ii < 2; ++ii) {
      const int n1 = n1g * 2 + ii;
      const float4 v0 = xb[(size_t)(n1)*256 + wl];
      const float4 v1 = xb[(size_t)(n1 + 64) * 256 + wl];
      const float4 v2 = xb[(size_t)(n1 + 128) * 256 + wl];
      const float4 v3 = xb[(size_t)(n1 + 192) * 256 + wl];
      {
        const float sx = v0.x + v2.x, sy = v0.w + v2.w;
        const float dx = v0.x - v2.x, dy = v0.w - v2.w;
        const float ux = v1.x + v3.x, uy = v1.w + v3.w;
        const float ex = v1.x - v3.x, ey = v1.w - v3.w;
        yf[n1][0][0][wl] = make_float2(sx + ux, sy + uy);
        yf[n1][2][0][wl] = make_float2(sx - ux, sy - uy);
        yf[n1][1][0][wl] = make_float2(dx + ey, dy - ex);
        yf[n1][3][0][wl] = make_float2(dx - ey, dy + ex);
      }
      {
        const float sx = v0.y + v2.y, sy = v0.z + v2.z;
        const float dx = v0.y - v2.y, dy = v0.z - v2.z;
        const float ux = v1.y + v3.y, uy = v1.z + v3.z;
        const float ex = v1.y - v3.y, ey = v1.z - v3.z;
        yf[n1][0][1][wl] = make_float2(sx + ux, sy + uy);
        yf[n1][2][1][wl] = make_float2(sx - ux, sy - uy);
        yf[n1][1][1][wl] = make_float2(dx + ey, dy - ex);
        yf[n1][3][1][wl] = make_float2(dx - ey, dy + ex);
      }
    }
  }
  __syncthreads();
  const int wl   = t & 7;
  const int dual = (t >> 3) & 1;
  const int kb   = t >> 4;
  const int r    = kb & 3;
  float2 acc[16];
#pragma unroll
  for (int c = 0; c < 16; ++c) acc[c] = make_float2(0.f, 0.f);
  int idx = 0;
#pragma unroll
  for (int n1 = 0; n1 < 64; ++n1) {
    const float2 tv = twn[idx];
    const float2 yv = yf[n1][r][dual][wl];
    cmac(acc[n1 & 15], yv, tv);
    idx = (idx + kb) & 255;
  }
  const float WC[16] = W16_C;
  const float WS[16] = W16_S;
  float2 D0 = make_float2(0.f, 0.f), D1 = D0, D2 = D0, D3 = D0;
#pragma unroll
  for (int c = 0; c < 16; ++c) {
    const float2 a = acc[c];
    const float cc = WC[c], ss = WS[c];
    const float cc2 = WC[(2 * c) & 15], ss2 = WS[(2 * c) & 15];
    D0.x += a.x;                         D0.y += a.y;
    D1.x = fmaf(a.x, cc,  fmaf( a.y, ss,  D1.x));
    D1.y = fmaf(a.y, cc,  fmaf(-a.x, ss,  D1.y));
    D2.x = fmaf(a.x, cc2, fmaf(-a.y, ss2, D2.x));
    D2.y = fmaf(a.y, cc2, fmaf( a.x, ss2, D2.y));
    D3.x = fmaf(a.x, cc,  fmaf(-a.y, ss,  D3.x));
    D3.y = fmaf(a.y, cc,  fmaf( a.x, ss,  D3.y));
  }
  float2* __restrict__ Gp = (float2*)G;
  const size_t base = ((size_t)(img * 2 + dual) * 64) * 256 + w0 + wl;
  Gp[base + (size_t)(kb)*256]      = D0;
  Gp[base + (size_t)(kb + 16)*256] = D1;
  Gp[base + (size_t)(kb + 32)*256] = D2;
  Gp[base + (size_t)(kb + 48)*256] = D3;
}

// ---------------------------------------------------------------------------
// F2 (v5): pruned DFT along W, mod-16 class accumulation (f1-style).
// grid 1024 (16 rows/block), block 256 = 16 kslot x 16 trow.
// ---------------------------------------------------------------------------
__global__ __launch_bounds__(256) void f2_dft_w(const float* __restrict__ G,
                                                float* __restrict__ mi) {
  __shared__ float2 twn[256];       // e^{-2pi i t/256}
  __shared__ float2 yf[16][65][4];  // [trow][n1][r], pad 65 -> trow on distinct banks
  const int t = threadIdx.x;
  {
    float sv, cv;
    sincosf(-TWO_PI * (float)t * (1.0f / 256.0f), &sv, &cv);
    twn[t] = make_float2(cv, sv);
  }
  const int row0 = blockIdx.x * 16;
  for (int idx = t; idx < 1024; idx += 256) {
    const int tr = idx >> 6, n1 = idx & 63;
    const float2* __restrict__ Gp = (const float2*)G + (size_t)(row0 + tr) * 256;
    const float2 z0 = Gp[n1], z1 = Gp[n1 + 64], z2 = Gp[n1 + 128], z3 = Gp[n1 + 192];
    const float sx = z0.x + z2.x, sy = z0.y + z2.y;
    const float dx = z0.x - z2.x, dy = z0.y - z2.y;
    const float ux = z1.x + z3.x, uy = z1.y + z3.y;
    const float ex = z1.x - z3.x, ey = z1.y - z3.y;
    yf[tr][n1][0] = make_float2(sx + ux, sy + uy);
    yf[tr][n1][2] = make_float2(sx - ux, sy - uy);
    yf[tr][n1][1] = make_float2(dx + ey, dy - ex);
    yf[tr][n1][3] = make_float2(dx - ey, dy + ex);
  }
  __syncthreads();
  const int kslot = t & 15;
  const int trow  = t >> 4;
  const int r     = kslot & 3;
  float2 acc[16];
#pragma unroll
  for (int c = 0; c < 16; ++c) acc[c] = make_float2(0.f, 0.f);
  int idx = 0;
#pragma unroll
  for (int n1 = 0; n1 < 64; ++n1) {
    const float2 tv = twn[idx];
    const float2 yv = yf[trow][n1][r];
    cmac(acc[n1 & 15], yv, tv);
    idx = (idx + kslot) & 255;
  }
  const float WC[16] = W16_C;
  const float WS[16] = W16_S;
  float2 D[4];
  D[0] = make_float2(0.f, 0.f); D[1] = D[0]; D[2] = D[0]; D[3] = D[0];
#pragma unroll
  for (int c = 0; c < 16; ++c) {
    const float2 a = acc[c];
    const float cc = WC[c], ss = WS[c];
    const float cc2 = WC[(2 * c) & 15], ss2 = WS[(2 * c) & 15];
    D[0].x += a.x;                        D[0].y += a.y;
    D[1].x = fmaf(a.x, cc,  fmaf( a.y, ss,  D[1].x));
    D[1].y = fmaf(a.y, cc,  fmaf(-a.x, ss,  D[1].y));
    D[2].x = fmaf(a.x, cc2, fmaf(-a.y, ss2, D[2].x));
    D[2].y = fmaf(a.y, cc2, fmaf( a.x, ss2, D[2].y));
    D[3].x = fmaf(a.x, cc,  fmaf(-a.y, ss,  D[3].x));
    D[3].y = fmaf(a.y, cc,  fmaf( a.x, ss,  D[3].y));
  }
  const int row  = row0 + trow;       // ((img*2+dual)*64 + kx)
  const int kx   = row & 63;
  const int dual = (row >> 6) & 1;
  const int bc   = row >> 7;
  const int b = bc >> 5, cc = bc & 31;
  const int sRe = dual ? 1 : 0;
  const int sIm = dual ? 2 : 3;
#pragma unroll
  for (int m = 0; m < 4; ++m) {
    const int kyi = kslot + (m << 4);
    const size_t moff = (size_t)kx * 64 + kyi;
    mi[(((size_t)(b * 4 + sRe)) * 32 + cc) * 4096 + moff] = D[m].x;
    mi[(((size_t)(b * 4 + sIm)) * 32 + cc) * 4096 + moff] = D[m].y;
  }
}

// ---------------------------------------------------------------------------
// EIN (v5): per-mode Clifford mix, 16-mode tiles, grid 512 (2 blocks/CU),
// block 256 = 16q x 16o, double-buffered weight prefetch.
// ---------------------------------------------------------------------------
__global__ __launch_bounds__(256) void ein_k(const float* __restrict__ mi,
                                             const float* __restrict__ wgt,
                                             float* __restrict__ mo) {
  __shared__ float si[4][128][16];  // [b][i=s*32+c][q]  32KB
  const int t = threadIdx.x;
  const int bid = blockIdx.x;
  const int m0 = (bid >> 1) << 4;
  const int oh = bid & 1;
  for (int idx = t; idx < 8192; idx += 256) {
    const int q = idx & 15, i = (idx >> 4) & 127, b = idx >> 11;
    si[b][i][q] = mi[((size_t)b * 128 + i) * 4096 + m0 + q];
  }
  __syncthreads();
  const int q = t & 15;
  const int o = oh * 16 + (t >> 4);
  const float* __restrict__ wb = wgt + (size_t)o * 32 * 4096 + m0 + q;
  float acc[4][4];
#pragma unroll
  for (int b = 0; b < 4; ++b)
#pragma unroll
    for (int r = 0; r < 4; ++r) acc[b][r] = 0.f;
  float wn[4];
#pragma unroll
  for (int j = 0; j < 4; ++j) wn[j] = wb[(size_t)j * 1024 * 4096];
#pragma unroll 1
  for (int c = 0; c < 32; ++c) {
    float wv[4];
#pragma unroll
    for (int j = 0; j < 4; ++j) wv[j] = wn[j];
    if (c < 31) {
#pragma unroll
      for (int j = 0; j < 4; ++j)
        wn[j] = wb[((size_t)j * 1024 + (c + 1)) * 4096];
    }
#pragma unroll
    for (int b = 0; b < 4; ++b) {
      const float iv0 = si[b][c][q];
      const float iv1 = si[b][32 + c][q];
      const float iv2 = si[b][64 + c][q];
      const float iv3 = si[b][96 + c][q];
      acc[b][0] += wv[0] * iv0 + wv[1] * iv1 + wv[2] * iv2 - wv[3] * iv3;
      acc[b][1] += wv[1] * iv0 + wv[0] * iv1 - wv[3] * iv2 + wv[2] * iv3;
      acc[b][2] += wv[2] * iv0 + wv[3] * iv1 + wv[0] * iv2 - wv[1] * iv3;
      acc[b][3] += wv[3] * iv0 + wv[2] * iv1 - wv[1] * iv2 + wv[0] * iv3;
    }
  }
#pragma unroll
  for (int b = 0; b < 4; ++b)
#pragma unroll
    for (int r = 0; r < 4; ++r)
      mo[(((size_t)b * 4 + r) * 32 + o) * 4096 + m0 + q] = acc[b][r];
}

// ---------------------------------------------------------------------------
// I1 (v5): inverse DFT along W via mod-16 classes + 16-pt DFT expansion.
// 16 outputs/thread.  grid 1024 (16 rows/block), block 256 = 16 n1 x 16 trow.
// ---------------------------------------------------------------------------
__global__ __launch_bounds__(256) void i1_idft_w(const float* __restrict__ mo,
                                                 float* __restrict__ T) {
  __shared__ float2 twc[256];       // e^{+2pi i t/256}
  __shared__ float2 srow[16][66];   // pad 66 -> trow groups on distinct banks
  const int t = threadIdx.x;
  {
    float sv, cv;
    sincosf(TWO_PI * (float)t * (1.0f / 256.0f), &sv, &cv);
    twc[t] = make_float2(cv, sv);
  }
  const int row0 = blockIdx.x * 16;
  for (int idx = t; idx < 1024; idx += 256) {
    const int tr = idx >> 6, ky = idx & 63;
    const int row = row0 + tr;        // ((bo*2+dual)*64 + kx)
    const int kx = row & 63;
    const int dual = (row >> 6) & 1;
    const int bo = row >> 7;
    const int b = bo >> 5, o = bo & 31;
    const int rA = dual ? 1 : 0;
    const int rB = dual ? 2 : 3;
    const size_t ib = (size_t)kx * 64 + ky;
    srow[tr][ky] = make_float2(mo[(((size_t)b * 4 + rA) * 32 + o) * 4096 + ib],
                               mo[(((size_t)b * 4 + rB) * 32 + o) * 4096 + ib]);
  }
  __syncthreads();
  const int n1   = t & 15;
  const int trow = t >> 4;
  float2 a[16];
#pragma unroll
  for (int c = 0; c < 16; ++c) a[c] = make_float2(0.f, 0.f);
  int idx = 0;                       // (kyf*n1) & 255
#pragma unroll
  for (int kyi = 0; kyi < 64; ++kyi) {
    if (kyi == 32) idx = (idx + 192 * n1) & 255;
    cmac(a[kyi & 15], srow[trow][kyi], twc[idx]);
    idx = (idx + n1) & 255;
  }
  const int row = row0 + trow;
  float2* __restrict__ Tp = (float2*)T + (size_t)row * 256;
#pragma unroll
  for (int p1 = 0; p1 < 4; ++p1) {
    float2 X[4];
    idft16_p1(a, p1, X);
#pragma unroll
    for (int p2 = 0; p2 < 4; ++p2)
      Tp[n1 + 16 * (p1 + 4 * p2)] = X[p2];
  }
}

// ---------------------------------------------------------------------------
// I2 (v4): inverse DFT along H, mod-16 classes + idft16 expansion. (unchanged)
// grid 2048, block 256.
// ---------------------------------------------------------------------------
__global__ __launch_bounds__(256) void i2_idft_h(const float* __restrict__ T,
                                                 float* __restrict__ out) {
  __shared__ float2 twc[256];       // e^{+2pi i t/256}
  __shared__ float2 Tl[2][64][16];
  const int t = threadIdx.x;
  {
    float sv, cv;
    sincosf(TWO_PI * (float)t * (1.0f / 256.0f), &sv, &cv);
    twc[t] = make_float2(cv, sv);
  }
  const int bid = blockIdx.x;
  const int bo = bid >> 4;
  const int w0 = (bid & 15) << 4;
  const float2* __restrict__ Tp = (const float2*)T + (size_t)bo * 32768;
  for (int idx = t; idx < 2048; idx += 256) {
    const int ww = idx & 15, kxi = (idx >> 4) & 63, dual = idx >> 10;
    Tl[dual][kxi][ww] = Tp[((size_t)dual * 64 + kxi) * 256 + w0 + ww];
  }
  __syncthreads();
  const int wl = t & 15;
  const int n1 = t >> 4;
  float2 a0[16], a1[16];
#pragma unroll
  for (int c = 0; c < 16; ++c) {
    a0[c] = make_float2(0.f, 0.f);
    a1[c] = make_float2(0.f, 0.f);
  }
  int idx = 0;
#pragma unroll
  for (int kxi = 0; kxi < 64; ++kxi) {
    if (kxi == 32) idx = (idx + 192 * n1) & 255;
    const float2 tv = twc[idx];
    cmac(a0[kxi & 15], Tl[0][kxi][wl], tv);
    cmac(a1[kxi & 15], Tl[1][kxi][wl], tv);
    idx = (idx + n1) & 255;
  }
  const float sc = 1.0f / 65536.0f;
  float4* __restrict__ op = (float4*)out + (size_t)bo * 65536 + w0 + wl;
#pragma unroll
  for (int p1 = 0; p1 < 4; ++p1) {
    float2 X0[4], X1[4];
    idft16_p1(a0, p1, X0);
    idft16_p1(a1, p1, X1);
#pragma unroll
    for (int p2 = 0; p2 < 4; ++p2) {
      const int h = n1 + 16 * (p1 + 4 * p2);
      op[(size_t)h * 256] = make_float4(X0[p2].x * sc, X1[p2].x * sc,
                                        X1[p2].y * sc, X0[p2].y * sc);
    }
  }
}

extern "C" void kernel_launch(void* const* d_in, const int* in_sizes, int n_in,
                              void* d_out, int out_size, void* d_ws, size_t ws_size,
                              hipStream_t stream) {
  const float* x = (const float*)d_in[0];
  const float* wgt = (const float*)d_in[1];
  float* out = (float*)d_out;
  float* G  = (float*)d_ws;        // 8,388,608 floats (33.5 MB), reused as T
  float* mi = G + 8388608;         // 2,097,152 floats
  float* mo = mi + 2097152;        // 2,097,152 floats

  hipLaunchKernelGGL(f1_dft_h, dim3(4096), dim3(256), 0, stream, x, G);
  hipLaunchKernelGGL(f2_dft_w, dim3(1024), dim3(256), 0, stream, G, mi);
  hipLaunchKernelGGL(ein_k,    dim3(512),  dim3(256), 0, stream, mi, wgt, mo);
  hipLaunchKernelGGL(i1_idft_w, dim3(1024), dim3(256), 0, stream, mo, G);
  hipLaunchKernelGGL(i2_idft_h, dim3(2048), dim3(256), 0, stream, G, out);
}

// Round 6
// 126.285 us; speedup vs baseline: 4.2398x; 1.0799x over previous
//
#include <hip/hip_runtime.h>
#include <hip/hip_fp16.h>
#include <math.h>

#define TWO_PI 6.28318530717958647692f

__device__ __forceinline__ void cmac(float2& a, const float2 b, const float2 c) {
  a.x = fmaf(b.x, c.x, fmaf(-b.y, c.y, a.x));
  a.y = fmaf(b.x, c.y, fmaf(b.y, c.x, a.y));
}
__device__ __forceinline__ __half2 pkh(const float xx, const float yy) {
  return __floats2half2_rn(xx, yy);
}
__device__ __forceinline__ float2 uph(const __half2 h) { return __half22float2(h); }

// cos/sin(2*pi*k/16), k=0..15 (positive exponent convention)
#define W16_C {1.f, 0.92387953f, 0.70710678f, 0.38268343f, 0.f, -0.38268343f, -0.70710678f, -0.92387953f, -1.f, -0.92387953f, -0.70710678f, -0.38268343f, 0.f, 0.38268343f, 0.70710678f, 0.92387953f}
#define W16_S {0.f, 0.38268343f, 0.70710678f, 0.92387953f, 1.f, 0.92387953f, 0.70710678f, 0.38268343f, 0.f, -0.38268343f, -0.70710678f, -0.92387953f, -1.f, -0.92387953f, -0.70710678f, -0.38268343f}

// 16-point +exponent DFT bins X[p1+4*p2], p2=0..3, from 16 classes a[c].
__device__ __forceinline__ void idft16_p1(const float2* a, const int p1,
                                          float2* X) {
  const float WC[16] = W16_C;
  const float WS[16] = W16_S;
  float2 tt[4];
#pragma unroll
  for (int r1 = 0; r1 < 4; ++r1) {
    const float2 q0 = a[r1], q1 = a[r1 + 4], q2 = a[r1 + 8], q3 = a[r1 + 12];
    const float2 s = make_float2(q0.x + q2.x, q0.y + q2.y);
    const float2 d = make_float2(q0.x - q2.x, q0.y - q2.y);
    const float2 u = make_float2(q1.x + q3.x, q1.y + q3.y);
    const float2 e = make_float2(q1.x - q3.x, q1.y - q3.y);
    float2 in;
    if (p1 == 0)      in = make_float2(s.x + u.x, s.y + u.y);
    else if (p1 == 1) in = make_float2(d.x - e.y, d.y + e.x);
    else if (p1 == 2) in = make_float2(s.x - u.x, s.y - u.y);
    else              in = make_float2(d.x + e.y, d.y - e.x);
    const float wc = WC[(r1 * p1) & 15], ws = WS[(r1 * p1) & 15];
    tt[r1] = make_float2(fmaf(in.x, wc, -in.y * ws), fmaf(in.y, wc, in.x * ws));
  }
  const float2 s = make_float2(tt[0].x + tt[2].x, tt[0].y + tt[2].y);
  const float2 d = make_float2(tt[0].x - tt[2].x, tt[0].y - tt[2].y);
  const float2 u = make_float2(tt[1].x + tt[3].x, tt[1].y + tt[3].y);
  const float2 e = make_float2(tt[1].x - tt[3].x, tt[1].y - tt[3].y);
  X[0] = make_float2(s.x + u.x, s.y + u.y);
  X[1] = make_float2(d.x - e.y, d.y + e.x);
  X[2] = make_float2(s.x - u.x, s.y - u.y);
  X[3] = make_float2(d.x + e.y, d.y - e.x);
}

// ---------------------------------------------------------------------------
// F1 (v6): pruned DFT along H, mod-16 classes, fp16 LDS tile + fp16 G out.
// w-tile 16, both duals per thread (shared twiddle), LDS repack epilogue for
// coalesced 64B G writes.  grid 2048 = 128 img * 16 w-tiles, block 256.
// ---------------------------------------------------------------------------
__global__ __launch_bounds__(256) void f1_dft_h(const float* __restrict__ x,
                                                __half2* __restrict__ G) {
  __shared__ float2 twn[256];           // e^{-2pi i t/256}
  __shared__ __half2 yf[64][4][20][2];  // [n1][r][wl(pad16->20)][dual]  40KB
  __shared__ __half2 dl[2][64][16];     // [dual][kx][w] repack buffer     8KB
  const int t = threadIdx.x;
  {
    float sv, cv;
    sincosf(-TWO_PI * (float)t * (1.0f / 256.0f), &sv, &cv);
    twn[t] = make_float2(cv, sv);
  }
  const int bid = blockIdx.x;
  const int img = bid >> 4;            // b*32+c
  const int w0  = (bid & 15) << 4;     // 16-column tile
  const float4* __restrict__ xb = (const float4*)x + (size_t)img * 65536 + w0;
  {
    const int wl  = t & 15;
    const int n1g = t >> 4;            // [0,16)
#pragma unroll
    for (int ii = 0; ii < 4; ++ii) {
      const int n1 = n1g + (ii << 4);
      const float4 v0 = xb[(size_t)(n1)*256 + wl];
      const float4 v1 = xb[(size_t)(n1 + 64) * 256 + wl];
      const float4 v2 = xb[(size_t)(n1 + 128) * 256 + wl];
      const float4 v3 = xb[(size_t)(n1 + 192) * 256 + wl];
      {  // dual 0: (comp0, comp3)
        const float sx = v0.x + v2.x, sy = v0.w + v2.w;
        const float dx = v0.x - v2.x, dy = v0.w - v2.w;
        const float ux = v1.x + v3.x, uy = v1.w + v3.w;
        const float ex = v1.x - v3.x, ey = v1.w - v3.w;
        yf[n1][0][wl][0] = pkh(sx + ux, sy + uy);
        yf[n1][2][wl][0] = pkh(sx - ux, sy - uy);
        yf[n1][1][wl][0] = pkh(dx + ey, dy - ex);
        yf[n1][3][wl][0] = pkh(dx - ey, dy + ex);
      }
      {  // dual 1: (comp1, comp2)
        const float sx = v0.y + v2.y, sy = v0.z + v2.z;
        const float dx = v0.y - v2.y, dy = v0.z - v2.z;
        const float ux = v1.y + v3.y, uy = v1.z + v3.z;
        const float ex = v1.y - v3.y, ey = v1.z - v3.z;
        yf[n1][0][wl][1] = pkh(sx + ux, sy + uy);
        yf[n1][2][wl][1] = pkh(sx - ux, sy - uy);
        yf[n1][1][wl][1] = pkh(dx + ey, dy - ex);
        yf[n1][3][wl][1] = pkh(dx - ey, dy + ex);
      }
    }
  }
  __syncthreads();
  const int wl = t & 15;
  const int kb = t >> 4;               // [0,16)
  const int r  = kb & 3;
  float2 a0[16], a1[16];
#pragma unroll
  for (int c = 0; c < 16; ++c) {
    a0[c] = make_float2(0.f, 0.f);
    a1[c] = make_float2(0.f, 0.f);
  }
  int idx = 0;                         // (n1*kb) & 255
#pragma unroll
  for (int n1 = 0; n1 < 64; ++n1) {
    const float2 tv = twn[idx];
    const float2 hv = *reinterpret_cast<const float2*>(&yf[n1][r][wl][0]);
    const float2 y0 = uph(__builtin_bit_cast(__half2, hv.x));
    const float2 y1 = uph(__builtin_bit_cast(__half2, hv.y));
    cmac(a0[n1 & 15], y0, tv);
    cmac(a1[n1 & 15], y1, tv);
    idx = (idx + kb) & 255;
  }
  const float WC[16] = W16_C;
  const float WS[16] = W16_S;
  float2 D0 = make_float2(0.f, 0.f), D1 = D0, D2 = D0, D3 = D0;
  float2 E0 = D0, E1 = D0, E2 = D0, E3 = D0;
#pragma unroll
  for (int c = 0; c < 16; ++c) {
    const float cc = WC[c], ss = WS[c];
    const float cc2 = WC[(2 * c) & 15], ss2 = WS[(2 * c) & 15];
    {
      const float2 a = a0[c];
      D0.x += a.x;                         D0.y += a.y;
      D1.x = fmaf(a.x, cc,  fmaf( a.y, ss,  D1.x));
      D1.y = fmaf(a.y, cc,  fmaf(-a.x, ss,  D1.y));
      D2.x = fmaf(a.x, cc2, fmaf(-a.y, ss2, D2.x));
      D2.y = fmaf(a.y, cc2, fmaf( a.x, ss2, D2.y));
      D3.x = fmaf(a.x, cc,  fmaf(-a.y, ss,  D3.x));
      D3.y = fmaf(a.y, cc,  fmaf( a.x, ss,  D3.y));
    }
    {
      const float2 a = a1[c];
      E0.x += a.x;                         E0.y += a.y;
      E1.x = fmaf(a.x, cc,  fmaf( a.y, ss,  E1.x));
      E1.y = fmaf(a.y, cc,  fmaf(-a.x, ss,  E1.y));
      E2.x = fmaf(a.x, cc2, fmaf(-a.y, ss2, E2.x));
      E2.y = fmaf(a.y, cc2, fmaf( a.x, ss2, E2.y));
      E3.x = fmaf(a.x, cc,  fmaf(-a.y, ss,  E3.x));
      E3.y = fmaf(a.y, cc,  fmaf( a.x, ss,  E3.y));
    }
  }
  dl[0][kb][wl]      = pkh(D0.x, D0.y);
  dl[0][kb + 16][wl] = pkh(D1.x, D1.y);
  dl[0][kb + 32][wl] = pkh(D2.x, D2.y);
  dl[0][kb + 48][wl] = pkh(D3.x, D3.y);
  dl[1][kb][wl]      = pkh(E0.x, E0.y);
  dl[1][kb + 16][wl] = pkh(E1.x, E1.y);
  dl[1][kb + 32][wl] = pkh(E2.x, E2.y);
  dl[1][kb + 48][wl] = pkh(E3.x, E3.y);
  __syncthreads();
  const __half2* __restrict__ dfl = &dl[0][0][0];
#pragma unroll
  for (int i = 0; i < 8; ++i) {
    const int flat = t + (i << 8);
    const int dual = flat >> 10, kx = (flat >> 4) & 63, w = flat & 15;
    const size_t row = (size_t)(img * 2 + dual) * 64 + kx;
    G[row * 256 + w0 + w] = dfl[flat];
  }
}

// ---------------------------------------------------------------------------
// F2 (v6): pruned DFT along W, mod-16 classes; fp16 G in, fp16 mi out.
// grid 1024 (16 rows/block), block 256 = 16 kslot x 16 trow.
// ---------------------------------------------------------------------------
__global__ __launch_bounds__(256) void f2_dft_w(const __half2* __restrict__ G,
                                                __half2* __restrict__ mi) {
  __shared__ float2 twn[256];
  __shared__ float2 yf[16][65][4];
  const int t = threadIdx.x;
  {
    float sv, cv;
    sincosf(-TWO_PI * (float)t * (1.0f / 256.0f), &sv, &cv);
    twn[t] = make_float2(cv, sv);
  }
  const int row0 = blockIdx.x * 16;
  for (int idx = t; idx < 1024; idx += 256) {
    const int tr = idx >> 6, n1 = idx & 63;
    const __half2* __restrict__ Gp = G + (size_t)(row0 + tr) * 256;
    const float2 z0 = uph(Gp[n1]), z1 = uph(Gp[n1 + 64]);
    const float2 z2 = uph(Gp[n1 + 128]), z3 = uph(Gp[n1 + 192]);
    const float sx = z0.x + z2.x, sy = z0.y + z2.y;
    const float dx = z0.x - z2.x, dy = z0.y - z2.y;
    const float ux = z1.x + z3.x, uy = z1.y + z3.y;
    const float ex = z1.x - z3.x, ey = z1.y - z3.y;
    yf[tr][n1][0] = make_float2(sx + ux, sy + uy);
    yf[tr][n1][2] = make_float2(sx - ux, sy - uy);
    yf[tr][n1][1] = make_float2(dx + ey, dy - ex);
    yf[tr][n1][3] = make_float2(dx - ey, dy + ex);
  }
  __syncthreads();
  const int kslot = t & 15;
  const int trow  = t >> 4;
  const int r     = kslot & 3;
  float2 acc[16];
#pragma unroll
  for (int c = 0; c < 16; ++c) acc[c] = make_float2(0.f, 0.f);
  int idx = 0;
#pragma unroll
  for (int n1 = 0; n1 < 64; ++n1) {
    const float2 tv = twn[idx];
    const float2 yv = yf[trow][n1][r];
    cmac(acc[n1 & 15], yv, tv);
    idx = (idx + kslot) & 255;
  }
  const float WC[16] = W16_C;
  const float WS[16] = W16_S;
  float2 D[4];
  D[0] = make_float2(0.f, 0.f); D[1] = D[0]; D[2] = D[0]; D[3] = D[0];
#pragma unroll
  for (int c = 0; c < 16; ++c) {
    const float2 a = acc[c];
    const float cc = WC[c], ss = WS[c];
    const float cc2 = WC[(2 * c) & 15], ss2 = WS[(2 * c) & 15];
    D[0].x += a.x;                        D[0].y += a.y;
    D[1].x = fmaf(a.x, cc,  fmaf( a.y, ss,  D[1].x));
    D[1].y = fmaf(a.y, cc,  fmaf(-a.x, ss,  D[1].y));
    D[2].x = fmaf(a.x, cc2, fmaf(-a.y, ss2, D[2].x));
    D[2].y = fmaf(a.y, cc2, fmaf( a.x, ss2, D[2].y));
    D[3].x = fmaf(a.x, cc,  fmaf(-a.y, ss,  D[3].x));
    D[3].y = fmaf(a.y, cc,  fmaf( a.x, ss,  D[3].y));
  }
  const int row  = row0 + trow;       // ((img*2+dual)*64 + kx)
  const int kx   = row & 63;
  const int dual = (row >> 6) & 1;
  const int bc   = row >> 7;
  const int b = bc >> 5, cc = bc & 31;
#pragma unroll
  for (int m = 0; m < 4; ++m) {
    const int kyi = kslot + (m << 4);
    mi[((size_t)((b * 2 + dual) * 32 + cc)) * 4096 + kx * 64 + kyi] =
        pkh(D[m].x, D[m].y);
  }
}

// ---------------------------------------------------------------------------
// EIN (v6): Clifford mix; fp16 mi/mo (half2 = (Re,Im) per dual); c-split
// 512-thread blocks (16 waves/CU) + 2-deep weight prefetch; LDS reduce.
// grid 512 = 256 mode-tiles(16) * 2 o-halves.
// ---------------------------------------------------------------------------
__global__ __launch_bounds__(512) void ein_k(const __half2* __restrict__ mi,
                                             const float* __restrict__ wgt,
                                             __half2* __restrict__ mo) {
  __shared__ float si[4][128][16];  // [b][s*32+c][q]  32KB
  const int t = threadIdx.x;
  const int bid = blockIdx.x;
  const int m0 = (bid >> 1) << 4;
  const int oh = bid & 1;
  for (int idx = t; idx < 4096; idx += 512) {
    const int q = idx & 15, c = (idx >> 4) & 31, dual = (idx >> 9) & 1, b = idx >> 10;
    const float2 f = uph(mi[((size_t)((b * 2 + dual) * 32 + c)) * 4096 + m0 + q]);
    if (dual == 0) { si[b][c][q] = f.x;      si[b][96 + c][q] = f.y; }
    else           { si[b][32 + c][q] = f.x; si[b][64 + c][q] = f.y; }
  }
  __syncthreads();
  const int q  = t & 15;
  const int o  = oh * 16 + ((t >> 4) & 15);
  const int ch = t >> 8;             // c-half
  const int c0 = ch << 4;
  const float* __restrict__ wb = wgt + (size_t)o * 131072 + m0 + q;
  float acc[4][4];
#pragma unroll
  for (int b = 0; b < 4; ++b)
#pragma unroll
    for (int r = 0; r < 4; ++r) acc[b][r] = 0.f;
  float wA[4], wB[4];
#pragma unroll
  for (int j = 0; j < 4; ++j) wA[j] = wb[(size_t)j * 4194304 + (size_t)c0 * 4096];
#pragma unroll
  for (int j = 0; j < 4; ++j) wB[j] = wb[(size_t)j * 4194304 + (size_t)(c0 + 1) * 4096];
#pragma unroll 1
  for (int c = c0; c < c0 + 16; ++c) {
    float wv[4];
#pragma unroll
    for (int j = 0; j < 4; ++j) { wv[j] = wA[j]; wA[j] = wB[j]; }
    if (c + 2 < c0 + 16) {
#pragma unroll
      for (int j = 0; j < 4; ++j)
        wB[j] = wb[(size_t)j * 4194304 + (size_t)(c + 2) * 4096];
    }
#pragma unroll
    for (int b = 0; b < 4; ++b) {
      const float iv0 = si[b][c][q];
      const float iv1 = si[b][32 + c][q];
      const float iv2 = si[b][64 + c][q];
      const float iv3 = si[b][96 + c][q];
      acc[b][0] += wv[0] * iv0 + wv[1] * iv1 + wv[2] * iv2 - wv[3] * iv3;
      acc[b][1] += wv[1] * iv0 + wv[0] * iv1 - wv[3] * iv2 + wv[2] * iv3;
      acc[b][2] += wv[2] * iv0 + wv[3] * iv1 + wv[0] * iv2 - wv[1] * iv3;
      acc[b][3] += wv[3] * iv0 + wv[2] * iv1 - wv[1] * iv2 + wv[0] * iv3;
    }
  }
  __syncthreads();                    // si reads done; reuse as reduce buffer
  float* __restrict__ red = &si[0][0][0];   // 256*17 = 4352 floats, fits
  if (ch == 1) {
    const int tt = t & 255;
#pragma unroll
    for (int b = 0; b < 4; ++b)
#pragma unroll
      for (int r = 0; r < 4; ++r) red[tt * 17 + b * 4 + r] = acc[b][r];
  }
  __syncthreads();
  if (ch == 0) {
#pragma unroll
    for (int b = 0; b < 4; ++b)
#pragma unroll
      for (int r = 0; r < 4; ++r) acc[b][r] += red[t * 17 + b * 4 + r];
#pragma unroll
    for (int b = 0; b < 4; ++b) {
      mo[((size_t)((b * 2 + 0) * 32 + o)) * 4096 + m0 + q] = pkh(acc[b][0], acc[b][3]);
      mo[((size_t)((b * 2 + 1) * 32 + o)) * 4096 + m0 + q] = pkh(acc[b][1], acc[b][2]);
    }
  }
}

// ---------------------------------------------------------------------------
// I1 (v6): inverse DFT along W, mod-16 classes + idft16; fp16 mo in, fp16 T out.
// grid 1024 (16 rows/block), block 256 = 16 n1 x 16 trow.
// ---------------------------------------------------------------------------
__global__ __launch_bounds__(256) void i1_idft_w(const __half2* __restrict__ mo,
                                                 __half2* __restrict__ T) {
  __shared__ float2 twc[256];       // e^{+2pi i t/256}
  __shared__ float2 srow[16][66];
  const int t = threadIdx.x;
  {
    float sv, cv;
    sincosf(TWO_PI * (float)t * (1.0f / 256.0f), &sv, &cv);
    twc[t] = make_float2(cv, sv);
  }
  const int row0 = blockIdx.x * 16;
  for (int idx = t; idx < 1024; idx += 256) {
    const int tr = idx >> 6, ky = idx & 63;
    const int row = row0 + tr;        // ((bo*2+dual)*64 + kx)
    const int kx = row & 63;
    const int dual = (row >> 6) & 1;
    const int bo = row >> 7;
    const int b = bo >> 5, o = bo & 31;
    srow[tr][ky] =
        uph(mo[((size_t)((b * 2 + dual) * 32 + o)) * 4096 + kx * 64 + ky]);
  }
  __syncthreads();
  const int n1   = t & 15;
  const int trow = t >> 4;
  float2 a[16];
#pragma unroll
  for (int c = 0; c < 16; ++c) a[c] = make_float2(0.f, 0.f);
  int idx = 0;                       // (kyf*n1) & 255
#pragma unroll
  for (int kyi = 0; kyi < 64; ++kyi) {
    if (kyi == 32) idx = (idx + 192 * n1) & 255;
    cmac(a[kyi & 15], srow[trow][kyi], twc[idx]);
    idx = (idx + n1) & 255;
  }
  const int row = row0 + trow;
  __half2* __restrict__ Tp = T + (size_t)row * 256;
#pragma unroll
  for (int p1 = 0; p1 < 4; ++p1) {
    float2 X[4];
    idft16_p1(a, p1, X);
#pragma unroll
    for (int p2 = 0; p2 < 4; ++p2)
      Tp[n1 + 16 * (p1 + 4 * p2)] = pkh(X[p2].x, X[p2].y);
  }
}

// ---------------------------------------------------------------------------
// I2 (v6): inverse DFT along H, mod-16 classes + idft16; fp16 T in, fp32 out.
// grid 2048 = 128 images * 16 w-tiles(16), block 256.
// ---------------------------------------------------------------------------
__global__ __launch_bounds__(256) void i2_idft_h(const __half2* __restrict__ T,
                                                 float* __restrict__ out) {
  __shared__ float2 twc[256];       // e^{+2pi i t/256}
  __shared__ float2 Tl[2][64][16];
  const int t = threadIdx.x;
  {
    float sv, cv;
    sincosf(TWO_PI * (float)t * (1.0f / 256.0f), &sv, &cv);
    twc[t] = make_float2(cv, sv);
  }
  const int bid = blockIdx.x;
  const int bo = bid >> 4;
  const int w0 = (bid & 15) << 4;
  const __half2* __restrict__ Tp = T + (size_t)bo * 32768;
  for (int idx = t; idx < 2048; idx += 256) {
    const int ww = idx & 15, kxi = (idx >> 4) & 63, dual = idx >> 10;
    Tl[dual][kxi][ww] = uph(Tp[((size_t)dual * 64 + kxi) * 256 + w0 + ww]);
  }
  __syncthreads();
  const int wl = t & 15;
  const int n1 = t >> 4;
  float2 a0[16], a1[16];
#pragma unroll
  for (int c = 0; c < 16; ++c) {
    a0[c] = make_float2(0.f, 0.f);
    a1[c] = make_float2(0.f, 0.f);
  }
  int idx = 0;
#pragma unroll
  for (int kxi = 0; kxi < 64; ++kxi) {
    if (kxi == 32) idx = (idx + 192 * n1) & 255;
    const float2 tv = twc[idx];
    cmac(a0[kxi & 15], Tl[0][kxi][wl], tv);
    cmac(a1[kxi & 15], Tl[1][kxi][wl], tv);
    idx = (idx + n1) & 255;
  }
  const float sc = 1.0f / 65536.0f;
  float4* __restrict__ op = (float4*)out + (size_t)bo * 65536 + w0 + wl;
#pragma unroll
  for (int p1 = 0; p1 < 4; ++p1) {
    float2 X0[4], X1[4];
    idft16_p1(a0, p1, X0);
    idft16_p1(a1, p1, X1);
#pragma unroll
    for (int p2 = 0; p2 < 4; ++p2) {
      const int h = n1 + 16 * (p1 + 4 * p2);
      op[(size_t)h * 256] = make_float4(X0[p2].x * sc, X1[p2].x * sc,
                                        X1[p2].y * sc, X0[p2].y * sc);
    }
  }
}

extern "C" void kernel_launch(void* const* d_in, const int* in_sizes, int n_in,
                              void* d_out, int out_size, void* d_ws, size_t ws_size,
                              hipStream_t stream) {
  const float* x = (const float*)d_in[0];
  const float* wgt = (const float*)d_in[1];
  float* out = (float*)d_out;
  __half2* G  = (__half2*)d_ws;     // 4,194,304 half2 (16.8 MB), reused as T
  __half2* mi = G + 4194304;        // 1,048,576 half2
  __half2* mo = mi + 1048576;       // 1,048,576 half2

  hipLaunchKernelGGL(f1_dft_h, dim3(2048), dim3(256), 0, stream, x, G);
  hipLaunchKernelGGL(f2_dft_w, dim3(1024), dim3(256), 0, stream, G, mi);
  hipLaunchKernelGGL(ein_k,    dim3(512),  dim3(512), 0, stream, mi, wgt, mo);
  hipLaunchKernelGGL(i1_idft_w, dim3(1024), dim3(256), 0, stream, mo, G);
  hipLaunchKernelGGL(i2_idft_h, dim3(2048), dim3(256), 0, stream, G, out);
}